// Round 6
// baseline (13728.499 us; speedup 1.0000x reference)
//
#include <hip/hip_runtime.h>
#include <math.h>
#include <stdint.h>

#define B_   32
#define TI_  128
#define TO_  64
#define E_   256
#define H_   512
#define A_   512
#define VO_  32000
#define G3_  1536   // 3H
#define D2H_ 1024   // 2H

using short8 = __attribute__((ext_vector_type(8))) short;
using f32x4  = __attribute__((ext_vector_type(4))) float;
typedef __attribute__((ext_vector_type(2))) __bf16 bf16x2_t;

__device__ __forceinline__ unsigned short f2bf(float x) {
  uint32_t u = __builtin_bit_cast(uint32_t, x);
  uint32_t r = (u + 0x7fffu + ((u >> 16) & 1u)) >> 16;
  return (unsigned short)r;
}
__device__ __forceinline__ uint32_t pack2(float lo, float hi) {
  return (uint32_t)f2bf(lo) | ((uint32_t)f2bf(hi) << 16);
}
__device__ __forceinline__ float bflo(uint32_t u) { return __builtin_bit_cast(float, u << 16); }
__device__ __forceinline__ float bfhi(uint32_t u) { return __builtin_bit_cast(float, u & 0xffff0000u); }

#if __has_builtin(__builtin_amdgcn_fdot2_f32_bf16)
__device__ __forceinline__ float dot2bf(uint32_t a, uint32_t b, float c) {
  return __builtin_amdgcn_fdot2_f32_bf16(__builtin_bit_cast(bf16x2_t, a),
                                         __builtin_bit_cast(bf16x2_t, b), c, false);
}
#else
__device__ __forceinline__ float dot2bf(uint32_t a, uint32_t b, float c) {
  return fmaf(bfhi(a), bfhi(b), fmaf(bflo(a), bflo(b), c));
}
#endif

__device__ __forceinline__ float sigf(float x) {
  return __builtin_amdgcn_rcpf(1.f + __expf(-x));
}
__device__ __forceinline__ float tanhf_(float x) {
  return fmaf(-2.f, __builtin_amdgcn_rcpf(1.f + __expf(2.f * x)), 1.f);
}

// ---------------- init: zero HAb tail rows ----------------------------------
__global__ __launch_bounds__(256) void k_init(unsigned short* __restrict__ tail) {
  int i = blockIdx.x * 256 + threadIdx.x;
  if (i < 32 * G3_) tail[i] = 0;
}

// ---------------- f32 -> bf16 row-major (8 elems/thread) --------------------
__global__ __launch_bounds__(256) void k_cvt_bf16(const float* __restrict__ in,
                                                  unsigned short* __restrict__ out, int n8) {
  int i = blockIdx.x * 256 + threadIdx.x;
  if (i >= n8) return;
  float4 a = ((const float4*)in)[2 * i];
  float4 b = ((const float4*)in)[2 * i + 1];
  uint4 o = { pack2(a.x, a.y), pack2(a.z, a.w), pack2(b.x, b.y), pack2(b.z, b.w) };
  ((uint4*)out)[i] = o;
}

// row-major bf16 conversions for MFMA GEMM operands
__global__ __launch_bounds__(256) void k_cvt_multi(
    const float* __restrict__ i0, unsigned short* __restrict__ o0,   // dWih  245760 u8
    const float* __restrict__ i1, unsigned short* __restrict__ o1,   // aWenc  65536
    const float* __restrict__ i2, unsigned short* __restrict__ o2,   // eWih_f 49152
    const float* __restrict__ i3, unsigned short* __restrict__ o3) { // eWih_b 49152
  int u = blockIdx.x * 256 + threadIdx.x;
  const float* in; unsigned short* out; int lu;
  if      (u < 245760) { in = i0; out = o0; lu = u; }
  else if (u < 311296) { in = i1; out = o1; lu = u - 245760; }
  else if (u < 360448) { in = i2; out = o2; lu = u - 311296; }
  else if (u < 409600) { in = i3; out = o3; lu = u - 360448; }
  else return;
  float4 a = ((const float4*)in)[2 * lu];
  float4 b = ((const float4*)in)[2 * lu + 1];
  uint4 o = { pack2(a.x, a.y), pack2(a.z, a.w), pack2(b.x, b.y), pack2(b.z, b.w) };
  ((uint4*)out)[lu] = o;
}

// W2 layout: uint2[kp][P], entry [kp][gg*256+cg] = { pack(W[gg*512+2cg][2kp..2kp+1]),
//                                                    pack(W[gg*512+2cg+1][2kp..2kp+1]) }
__global__ __launch_bounds__(256) void k_cvt_w2(
    const float* __restrict__ i0, uint2* __restrict__ o0,   // eWhh_f 196608
    const float* __restrict__ i1, uint2* __restrict__ o1,   // eWhh_b 196608
    const float* __restrict__ i2, uint2* __restrict__ o2,   // dWhh   196608
    const float* __restrict__ i3, uint2* __restrict__ o3) { // aWdec   65536 (P=256)
  int u = blockIdx.x * 256 + threadIdx.x;
  const float* in; uint2* out; int lu, perkp;
  if      (u < 196608) { in = i0; out = o0; lu = u;          perkp = 768; }
  else if (u < 393216) { in = i1; out = o1; lu = u - 196608; perkp = 768; }
  else if (u < 589824) { in = i2; out = o2; lu = u - 393216; perkp = 768; }
  else if (u < 655360) { in = i3; out = o3; lu = u - 589824; perkp = 256; }
  else return;
  int kp = lu / perkp, rest = lu % perkp;
  int gg = rest >> 8, cg = rest & 255;
  int row0 = gg * 512 + 2 * cg;
  const float* p0 = in + (size_t)row0 * 512 + 2 * kp;
  const float* p1 = p0 + 512;
  uint2 o = { pack2(p0[0], p0[1]), pack2(p1[0], p1[1]) };
  out[lu] = o;
}

// EW2: encWA bf16 [4096][1536] -> uint2 [b][tp][gg*256+cg]
//   .x = {encWA[b,2tp,col0], encWA[b,2tp+1,col0]}, .y = same col0+1
__global__ __launch_bounds__(256) void k_packT2(const unsigned short* __restrict__ encWA,
                                                uint2* __restrict__ EW2) {
  int idx = blockIdx.x * 256 + threadIdx.x;
  if (idx >= 32 * 64 * 768) return;
  int rest = idx % 768, q = idx / 768;
  int tp = q & 63, b = q >> 6;
  int gg = rest >> 8, cg = rest & 255;
  int col0 = gg * 512 + 2 * cg;
  size_t r0 = ((size_t)(b * 128 + 2 * tp)) * 1536;
  size_t r1 = r0 + 1536;
  uint2 o;
  o.x = (uint32_t)encWA[r0 + col0] | ((uint32_t)encWA[r1 + col0] << 16);
  o.y = (uint32_t)encWA[r0 + col0 + 1] | ((uint32_t)encWA[r1 + col0 + 1] << 16);
  EW2[idx] = o;
}

// ---------------- embedding gathers (bf16 out) ------------------------------
__global__ __launch_bounds__(256) void k_gather_xb(const int* __restrict__ inp,
                                                   const float* __restrict__ emb,
                                                   unsigned short* __restrict__ xb) {
  int idx = blockIdx.x * 256 + threadIdx.x;
  if (idx >= 4096 * 32) return;
  int row = idx >> 5, e8 = idx & 31;
  int tok = inp[row];
  const float4* s = (const float4*)(emb + (size_t)tok * E_ + e8 * 8);
  float4 a = s[0], b = s[1];
  uint4 o = { pack2(a.x, a.y), pack2(a.z, a.w), pack2(b.x, b.y), pack2(b.z, b.w) };
  ((uint4*)xb)[idx] = o;
}

__global__ __launch_bounds__(256) void k_gather_xeb(const int* __restrict__ outi,
                                                    const float* __restrict__ emb,
                                                    unsigned short* __restrict__ xeb) {
  int idx = blockIdx.x * 256 + threadIdx.x;
  if (idx >= 2016 * 32) return;
  int row = idx >> 5, e8 = idx & 31;
  int i = row >> 5, b = row & 31;
  int tok = outi[b * TO_ + i];
  const float4* s = (const float4*)(emb + (size_t)tok * E_ + e8 * 8);
  float4 a = s[0], bb = s[1];
  uint4 o = { pack2(a.x, a.y), pack2(a.z, a.w), pack2(bb.x, bb.y), pack2(bb.z, bb.w) };
  ((uint4*)xeb)[idx] = o;
}

__global__ __launch_bounds__(256) void k_first(float* __restrict__ dout) {
  int idx = blockIdx.x * 256 + threadIdx.x;
  if (idx >= B_ * VO_) return;
  int b = idx / VO_, v = idx % VO_;
  dout[(size_t)b * TO_ * VO_ + v] = (v == 1) ? 0.f : -20.72326583694641f;
}

// ---------------- generic bf16 MFMA GEMM (m97 structure) ---------------------
template <int MODE>
__global__ __launch_bounds__(256) void k_bgemm(
    const unsigned short* __restrict__ A, int lda,
    const unsigned short* __restrict__ Bt, int ldb,
    const float* __restrict__ bias,
    void* __restrict__ Cv, int ldc, int M, int N, int K) {
  __shared__ alignas(16) unsigned short As[128 * 32];
  __shared__ alignas(16) unsigned short Bs[128 * 32];
  const int tid = threadIdx.x;
  const int wave = tid >> 6, lane = tid & 63;
  const int m0 = blockIdx.y * 128, n0 = blockIdx.x * 128;
  const int wr = wave >> 1, wc = wave & 1;

  f32x4 acc[4][4];
#pragma unroll
  for (int i = 0; i < 4; ++i)
#pragma unroll
    for (int j = 0; j < 4; ++j) acc[i][j] = (f32x4){0.f, 0.f, 0.f, 0.f};

  const int srow = tid >> 2;
  const int sbyte = (tid & 3) * 16;
  const int fr = lane & 15;
  const int fkb = (lane >> 4) * 16;

  for (int k0 = 0; k0 < K; k0 += 32) {
#pragma unroll
    for (int rd = 0; rd < 2; ++rd) {
      int row = rd * 64 + srow;
      int ra = min(m0 + row, M - 1);
      const char* ga = (const char*)(A + (size_t)ra * lda + k0) + sbyte;
      const char* gb = (const char*)(Bt + (size_t)(n0 + row) * ldb + k0) + sbyte;
      __builtin_amdgcn_global_load_lds(
          (const __attribute__((address_space(1))) uint32_t*)ga,
          (__attribute__((address_space(3))) uint32_t*)((char*)As + rd * 4096 + wave * 1024),
          16, 0, 0);
      __builtin_amdgcn_global_load_lds(
          (const __attribute__((address_space(1))) uint32_t*)gb,
          (__attribute__((address_space(3))) uint32_t*)((char*)Bs + rd * 4096 + wave * 1024),
          16, 0, 0);
    }
    __syncthreads();

    short8 af[4], bf[4];
#pragma unroll
    for (int i = 0; i < 4; ++i) {
      int ar = wr * 64 + i * 16 + fr;
      int bc = wc * 64 + i * 16 + fr;
      af[i] = *(const short8*)((const char*)As + ar * 64 + fkb);
      bf[i] = *(const short8*)((const char*)Bs + bc * 64 + fkb);
    }
#pragma unroll
    for (int i = 0; i < 4; ++i)
#pragma unroll
      for (int j = 0; j < 4; ++j)
        acc[i][j] = __builtin_amdgcn_mfma_f32_16x16x32_bf16(af[i], bf[j], acc[i][j], 0, 0, 0);
    __syncthreads();
  }

  const int crow = (lane >> 4) * 4, ccol = lane & 15;
#pragma unroll
  for (int i = 0; i < 4; ++i) {
#pragma unroll
    for (int r = 0; r < 4; ++r) {
      int m = m0 + wr * 64 + i * 16 + crow + r;
      if (m >= M) continue;
#pragma unroll
      for (int j = 0; j < 4; ++j) {
        int n = n0 + wc * 64 + j * 16 + ccol;
        float v = acc[i][j][r] + (bias ? bias[n] : 0.f);
        if (MODE == 0) {
          ((float*)Cv)[(size_t)m * ldc + n] = v;
        } else if (MODE == 1) {
          ((unsigned short*)Cv)[(size_t)m * ldc + n] = f2bf(v);
        } else {
          int bb = m & 31, st = m >> 5;
          ((float*)Cv)[((size_t)bb * TO_ + st + 1) * VO_ + n] = v;
        }
      }
    }
  }
}

// ---------------- persistent encoder: 64 chains, 1024 thr -------------------
// thread: cg = tid>>2 (col pair), kq = tid&3 (k quarter). Double-buffered
// uint2 weight stream; padded LDS h-broadcast; shfl reduce over 4 lanes.
__global__ __launch_bounds__(1024, 4) void k_encoder(
    const unsigned short* __restrict__ xpb_f, const unsigned short* __restrict__ xpb_b,
    const uint2* __restrict__ W2f, const float* __restrict__ bhh_f,
    const uint2* __restrict__ W2b, const float* __restrict__ bhh_b,
    unsigned short* __restrict__ encb) {
  __shared__ uint32_t hb2p[260];
  __shared__ float hf[512];
  const int bid = blockIdx.x;
  const int dir = bid >> 5, b = bid & 31;
  const unsigned short* xpb = dir ? xpb_b : xpb_f;
  const uint2* W2 = dir ? W2b : W2f;
  const float* bhh = dir ? bhh_b : bhh_f;
  const int tid = threadIdx.x;
  const int cg = tid >> 2, kq = tid & 3;
  const int c0 = 2 * cg, c1 = c0 + 1;

  if (tid < 512) hf[tid] = 0.f;
  if (tid < 260) hb2p[tid] = 0u;
  float br0 = 0, br1 = 0, bz0 = 0, bz1 = 0, bn0 = 0, bn1 = 0;
  if (kq == 0) {
    br0 = bhh[c0]; br1 = bhh[c1];
    bz0 = bhh[512 + c0]; bz1 = bhh[512 + c1];
    bn0 = bhh[1024 + c0]; bn1 = bhh[1024 + c1];
  }
  const uint2* wbase = W2 + (size_t)(kq * 64) * 768 + cg;
  const uint32_t* hq = hb2p + kq * 65;
  uint32_t* encw = (uint32_t*)encb;
  __syncthreads();

  for (int t = 0; t < TI_; ++t) {
    const int tt = dir ? (TI_ - 1 - t) : t;
    float ar0 = 0, ar1 = 0, az0 = 0, az1 = 0, an0 = 0, an1 = 0;
    {
      const uint2* wp = wbase;
      uint2 buf[2][3][4];
#pragma unroll
      for (int j = 0; j < 4; ++j) {
        buf[0][0][j] = wp[(size_t)j * 768];
        buf[0][1][j] = wp[(size_t)j * 768 + 256];
        buf[0][2][j] = wp[(size_t)j * 768 + 512];
      }
      wp += 4 * 768;
#pragma unroll
      for (int c = 0; c < 16; ++c) {
        const int cur = c & 1, nxt = cur ^ 1;
        if (c < 15) {
#pragma unroll
          for (int j = 0; j < 4; ++j) {
            buf[nxt][0][j] = wp[(size_t)j * 768];
            buf[nxt][1][j] = wp[(size_t)j * 768 + 256];
            buf[nxt][2][j] = wp[(size_t)j * 768 + 512];
          }
          wp += 4 * 768;
        }
#pragma unroll
        for (int j = 0; j < 4; ++j) {
          uint32_t hv = hq[c * 4 + j];
          ar0 = dot2bf(hv, buf[cur][0][j].x, ar0);
          ar1 = dot2bf(hv, buf[cur][0][j].y, ar1);
          az0 = dot2bf(hv, buf[cur][1][j].x, az0);
          az1 = dot2bf(hv, buf[cur][1][j].y, az1);
          an0 = dot2bf(hv, buf[cur][2][j].x, an0);
          an1 = dot2bf(hv, buf[cur][2][j].y, an1);
        }
      }
    }
    ar0 += __shfl_xor(ar0, 1); ar0 += __shfl_xor(ar0, 2);
    ar1 += __shfl_xor(ar1, 1); ar1 += __shfl_xor(ar1, 2);
    az0 += __shfl_xor(az0, 1); az0 += __shfl_xor(az0, 2);
    az1 += __shfl_xor(az1, 1); az1 += __shfl_xor(az1, 2);
    an0 += __shfl_xor(an0, 1); an0 += __shfl_xor(an0, 2);
    an1 += __shfl_xor(an1, 1); an1 += __shfl_xor(an1, 2);

    float hn0 = 0.f, hn1 = 0.f;
    if (kq == 0) {
      const uint32_t* xr = (const uint32_t*)(xpb + (size_t)(b * 128 + tt) * G3_);
      uint32_t uxr = xr[cg], uxz = xr[256 + cg], uxn = xr[512 + cg];
      float r0 = sigf(bflo(uxr) + ar0 + br0);
      float r1 = sigf(bfhi(uxr) + ar1 + br1);
      float z0 = sigf(bflo(uxz) + az0 + bz0);
      float z1 = sigf(bfhi(uxz) + az1 + bz1);
      float n0 = tanhf_(bflo(uxn) + r0 * (an0 + bn0));
      float n1 = tanhf_(bfhi(uxn) + r1 * (an1 + bn1));
      hn0 = (1.f - z0) * n0 + z0 * hf[c0];
      hn1 = (1.f - z1) * n1 + z1 * hf[c1];
      encw[(size_t)(b * 128 + tt) * 512 + dir * 256 + cg] = pack2(hn0, hn1);
    }
    __syncthreads();
    if (kq == 0) {
      hf[c0] = hn0; hf[c1] = hn1;
      hb2p[cg + (cg >> 6)] = pack2(hn0, hn1);
    }
    __syncthreads();
  }
}

// ---------------- persistent decoder: 32 chains, 1024 thr -------------------
__global__ __launch_bounds__(1024, 4) void k_decoder(
    const int* __restrict__ inp,
    const unsigned short* __restrict__ encb,
    const unsigned short* __restrict__ encpb,
    const float* __restrict__ XE,
    const uint2* __restrict__ EW2,     // [b][tp][gg*256+cg]
    const uint2* __restrict__ WH2,     // [kp][gg*256+cg]
    const uint2* __restrict__ WD2,     // [kp][cg]
    const float* __restrict__ dsW, const float* __restrict__ dsb,
    const float* __restrict__ dbhh,
    const float* __restrict__ abdec, const float* __restrict__ abenc,
    const float* __restrict__ av, const float* __restrict__ avb,
    unsigned short* __restrict__ HAb) {
  __shared__ uint32_t hb2p[260];
  __shared__ float hf[512];
  __shared__ uint32_t prb2[64];
  __shared__ float pr[128];
  __shared__ float sc[128];
  __shared__ float msk[128];
  __shared__ float dp[512];
  __shared__ float vavf[512];
  __shared__ float red[1024];
  __shared__ float red2[1024];
  __shared__ float dpx[4];
  const int b = blockIdx.x, tid = threadIdx.x;
  const int cg = tid >> 2, kq = tid & 3;
  const int c0 = 2 * cg, c1 = c0 + 1;
  const uint32_t* hq = hb2p + kq * 65;

  float db_r0 = 0, db_r1 = 0, db_z0 = 0, db_z1 = 0, db_n0 = 0, db_n1 = 0;
  float adb0 = 0, adb1 = 0;
  if (kq == 0) {
    db_r0 = dbhh[c0]; db_r1 = dbhh[c1];
    db_z0 = dbhh[512 + c0]; db_z1 = dbhh[512 + c1];
    db_n0 = dbhh[1024 + c0]; db_n1 = dbhh[1024 + c1];
    adb0 = abdec[c0] + abenc[c0];
    adb1 = abdec[c1] + abenc[c1];
  }
  const float avb0 = avb[0];

  if (tid < 128) msk[tid] = (inp[b * TI_ + tid] != 0) ? 1.f : 0.f;
  if (tid < 512) vavf[tid] = av[tid];
  __syncthreads();
  if (tid < 64) {
    float s = msk[tid] + msk[tid + 64];
#pragma unroll
    for (int o = 32; o > 0; o >>= 1) s += __shfl_xor(s, o);
    if (tid == 0) dpx[0] = s;
  }
  __syncthreads();
  const int len = min((int)dpx[0], TI_ - 1);

  // ---- dec0: h0 = enc[b,len] @ dsW^T + dsb (col = tid>>1, kh = tid&1) ----
  if (tid < 512) {
    uint32_t u = ((const uint32_t*)encb)[(size_t)(b * 128 + len) * 512 + tid];
    red[2 * tid] = bflo(u);
    red[2 * tid + 1] = bfhi(u);
  }
  __syncthreads();
  {
    const int col = tid >> 1, kh = tid & 1;
    const float4* w = (const float4*)(dsW + (size_t)col * D2H_ + kh * 512);
    float acc = 0.f;
#pragma unroll 8
    for (int k = 0; k < 128; ++k) {
      float4 l = ((const float4*)red)[kh * 128 + k];
      float4 q = w[k];
      acc = fmaf(l.x, q.x, fmaf(l.y, q.y, fmaf(l.z, q.z, fmaf(l.w, q.w, acc))));
    }
    acc += __shfl_xor(acc, 1);
    __syncthreads();
    if (kh == 0) hf[col] = acc + dsb[col];
    __syncthreads();
    if (tid < 256) hb2p[tid + (tid >> 6)] = pack2(hf[2 * tid], hf[2 * tid + 1]);
    __syncthreads();
  }

  auto attend = [&](int step) {
    // dp = h @ Wdec^T + bdec + benc  (uint2 stream, dbuf)
    {
      const uint2* wp = WD2 + (size_t)(kq * 64) * 256 + cg;
      float d0 = 0.f, d1 = 0.f;
      uint2 bufd[2][4];
#pragma unroll
      for (int j = 0; j < 4; ++j) bufd[0][j] = wp[(size_t)j * 256];
      wp += 4 * 256;
#pragma unroll
      for (int c = 0; c < 16; ++c) {
        const int cur = c & 1, nxt = cur ^ 1;
        if (c < 15) {
#pragma unroll
          for (int j = 0; j < 4; ++j) bufd[nxt][j] = wp[(size_t)j * 256];
          wp += 4 * 256;
        }
#pragma unroll
        for (int j = 0; j < 4; ++j) {
          uint32_t hv = hq[c * 4 + j];
          d0 = dot2bf(hv, bufd[cur][j].x, d0);
          d1 = dot2bf(hv, bufd[cur][j].y, d1);
        }
      }
      d0 += __shfl_xor(d0, 1); d0 += __shfl_xor(d0, 2);
      d1 += __shfl_xor(d1, 1); d1 += __shfl_xor(d1, 2);
      if (kq == 0) { dp[c0] = d0 + adb0; dp[c1] = d1 + adb1; }
    }
    __syncthreads();
    // scores: 8 threads per t
    {
      int t = tid >> 3, s8 = tid & 7;
      const uint32_t* ep = (const uint32_t*)encpb + (size_t)(b * 128 + t) * 256 + s8;
      float s = 0.f;
#pragma unroll 4
      for (int i = 0; i < 32; ++i) {
        int j = s8 + 8 * i;
        uint32_t u = ep[8 * i];
        float2 d2 = *(const float2*)&dp[2 * j];
        float2 v2 = *(const float2*)&vavf[2 * j];
        s = fmaf(v2.x, tanhf_(bflo(u) + d2.x), s);
        s = fmaf(v2.y, tanhf_(bfhi(u) + d2.y), s);
      }
      s += __shfl_xor(s, 1);
      s += __shfl_xor(s, 2);
      s += __shfl_xor(s, 4);
      if (s8 == 0) sc[t] = s;
    }
    __syncthreads();
    if (tid < 128) sc[tid] = (msk[tid] > 0.f) ? sc[tid] + avb0 : -1e30f;
    __syncthreads();
    if (tid < 64) {
      float m = fmaxf(sc[tid], sc[tid + 64]);
#pragma unroll
      for (int o = 32; o > 0; o >>= 1) m = fmaxf(m, __shfl_xor(m, o));
      if (tid == 0) dpx[1] = m;
    }
    __syncthreads();
    if (tid < 128) pr[tid] = __expf(sc[tid] - dpx[1]);
    __syncthreads();
    if (tid < 64) {
      float s2 = pr[tid] + pr[tid + 64];
#pragma unroll
      for (int o = 32; o > 0; o >>= 1) s2 += __shfl_xor(s2, o);
      if (tid == 0) dpx[2] = s2;
    }
    __syncthreads();
    float inv = __builtin_amdgcn_rcpf(dpx[2]);
    if (tid < 128) pr[tid] *= inv;
    __syncthreads();
    if (tid < 64) prb2[tid] = pack2(pr[2 * tid], pr[2 * tid + 1]);
    if (step >= 0) {
      // context = pr @ enc[b] -> HAb a-part
      const uint32_t* eb = (const uint32_t*)encb + (size_t)b * 128 * 512;
      int d = tid & 511, tq = tid >> 9;
      float x0 = 0.f, x1 = 0.f;
#pragma unroll 4
      for (int k = 0; k < 64; ++k) {
        int t = tq * 64 + k;
        float p = pr[t];
        uint32_t u = eb[(size_t)t * 512 + d];
        x0 = fmaf(p, bflo(u), x0);
        x1 = fmaf(p, bfhi(u), x1);
      }
      red[tid] = x0; red2[tid] = x1;
      __syncthreads();
      if (tid < 512) {
        x0 = red[tid] + red[tid + 512];
        x1 = red2[tid] + red2[tid + 512];
        uint32_t* hrow = (uint32_t*)(HAb + ((size_t)step * 32 + b) * G3_);
        hrow[256 + tid] = pack2(x0, x1);
      }
    }
    __syncthreads();
  };

  auto gru = [&](int i) {
    float xr0 = 0, xr1 = 0, xz0 = 0, xz1 = 0, xn0 = 0, xn1 = 0;
    // x-side: pr @ encW[b] (uint2 stream over 16 tp per quarter, dbuf chunks of 2)
    {
      const uint2* ep = EW2 + ((size_t)b * 64 + kq * 16) * 768 + cg;
      uint2 bufe[2][3][2];
#pragma unroll
      for (int j = 0; j < 2; ++j) {
        bufe[0][0][j] = ep[(size_t)j * 768];
        bufe[0][1][j] = ep[(size_t)j * 768 + 256];
        bufe[0][2][j] = ep[(size_t)j * 768 + 512];
      }
      ep += 2 * 768;
#pragma unroll
      for (int c = 0; c < 8; ++c) {
        const int cur = c & 1, nxt = cur ^ 1;
        if (c < 7) {
#pragma unroll
          for (int j = 0; j < 2; ++j) {
            bufe[nxt][0][j] = ep[(size_t)j * 768];
            bufe[nxt][1][j] = ep[(size_t)j * 768 + 256];
            bufe[nxt][2][j] = ep[(size_t)j * 768 + 512];
          }
          ep += 2 * 768;
        }
#pragma unroll
        for (int j = 0; j < 2; ++j) {
          uint32_t pv = prb2[kq * 16 + c * 2 + j];
          xr0 = dot2bf(pv, bufe[cur][0][j].x, xr0);
          xr1 = dot2bf(pv, bufe[cur][0][j].y, xr1);
          xz0 = dot2bf(pv, bufe[cur][1][j].x, xz0);
          xz1 = dot2bf(pv, bufe[cur][1][j].y, xz1);
          xn0 = dot2bf(pv, bufe[cur][2][j].x, xn0);
          xn1 = dot2bf(pv, bufe[cur][2][j].y, xn1);
        }
      }
    }
    float hr0 = 0, hr1 = 0, hz0 = 0, hz1 = 0, hn0_ = 0, hn1_ = 0;
    // h-side: h @ Whh^T
    {
      const uint2* wp = WH2 + (size_t)(kq * 64) * 768 + cg;
      uint2 buf[2][3][4];
#pragma unroll
      for (int j = 0; j < 4; ++j) {
        buf[0][0][j] = wp[(size_t)j * 768];
        buf[0][1][j] = wp[(size_t)j * 768 + 256];
        buf[0][2][j] = wp[(size_t)j * 768 + 512];
      }
      wp += 4 * 768;
#pragma unroll
      for (int c = 0; c < 16; ++c) {
        const int cur = c & 1, nxt = cur ^ 1;
        if (c < 15) {
#pragma unroll
          for (int j = 0; j < 4; ++j) {
            buf[nxt][0][j] = wp[(size_t)j * 768];
            buf[nxt][1][j] = wp[(size_t)j * 768 + 256];
            buf[nxt][2][j] = wp[(size_t)j * 768 + 512];
          }
          wp += 4 * 768;
        }
#pragma unroll
        for (int j = 0; j < 4; ++j) {
          uint32_t hv = hq[c * 4 + j];
          hr0 = dot2bf(hv, buf[cur][0][j].x, hr0);
          hr1 = dot2bf(hv, buf[cur][0][j].y, hr1);
          hz0 = dot2bf(hv, buf[cur][1][j].x, hz0);
          hz1 = dot2bf(hv, buf[cur][1][j].y, hz1);
          hn0_ = dot2bf(hv, buf[cur][2][j].x, hn0_);
          hn1_ = dot2bf(hv, buf[cur][2][j].y, hn1_);
        }
      }
    }
    float tr0 = xr0 + hr0; tr0 += __shfl_xor(tr0, 1); tr0 += __shfl_xor(tr0, 2);
    float tr1 = xr1 + hr1; tr1 += __shfl_xor(tr1, 1); tr1 += __shfl_xor(tr1, 2);
    float tz0 = xz0 + hz0; tz0 += __shfl_xor(tz0, 1); tz0 += __shfl_xor(tz0, 2);
    float tz1 = xz1 + hz1; tz1 += __shfl_xor(tz1, 1); tz1 += __shfl_xor(tz1, 2);
    xn0 += __shfl_xor(xn0, 1); xn0 += __shfl_xor(xn0, 2);
    xn1 += __shfl_xor(xn1, 1); xn1 += __shfl_xor(xn1, 2);
    hn0_ += __shfl_xor(hn0_, 1); hn0_ += __shfl_xor(hn0_, 2);
    hn1_ += __shfl_xor(hn1_, 1); hn1_ += __shfl_xor(hn1_, 2);

    float hnew0 = 0.f, hnew1 = 0.f;
    if (kq == 0) {
      const float* xrow = XE + ((size_t)i * 32 + b) * G3_;
      float r0 = sigf(xrow[c0] + tr0 + db_r0);
      float r1 = sigf(xrow[c1] + tr1 + db_r1);
      float z0 = sigf(xrow[512 + c0] + tz0 + db_z0);
      float z1 = sigf(xrow[512 + c1] + tz1 + db_z1);
      float n0 = tanhf_(xrow[1024 + c0] + xn0 + r0 * (hn0_ + db_n0));
      float n1 = tanhf_(xrow[1024 + c1] + xn1 + r1 * (hn1_ + db_n1));
      hnew0 = (1.f - z0) * n0 + z0 * hf[c0];
      hnew1 = (1.f - z1) * n1 + z1 * hf[c1];
      ((uint32_t*)(HAb + ((size_t)i * 32 + b) * G3_))[cg] = pack2(hnew0, hnew1);
    }
    __syncthreads();
    if (kq == 0) {
      hf[c0] = hnew0; hf[c1] = hnew1;
      hb2p[cg + (cg >> 6)] = pack2(hnew0, hnew1);
    }
    __syncthreads();
  };

  attend(-1);
  for (int i = 0; i < 63; ++i) {
    gru(i);
    attend(i);
  }
}

// ---------------- launch ------------------------------------------------------

extern "C" void kernel_launch(void* const* d_in, const int* in_sizes, int n_in,
                              void* d_out, int out_size, void* d_ws, size_t ws_size,
                              hipStream_t stream) {
  const int*   inp     = (const int*)d_in[0];
  const int*   outi    = (const int*)d_in[1];
  const float* emb_inp = (const float*)d_in[2];
  const float* emb_out = (const float*)d_in[3];
  const float* eWih_f  = (const float*)d_in[4];
  const float* eWhh_f  = (const float*)d_in[5];
  const float* ebih_f  = (const float*)d_in[6];
  const float* ebhh_f  = (const float*)d_in[7];
  const float* eWih_b  = (const float*)d_in[8];
  const float* eWhh_b  = (const float*)d_in[9];
  const float* ebih_b  = (const float*)d_in[10];
  const float* ebhh_b  = (const float*)d_in[11];
  const float* dsW     = (const float*)d_in[12];
  const float* dsb     = (const float*)d_in[13];
  const float* dWih    = (const float*)d_in[14];
  const float* dWhh    = (const float*)d_in[15];
  const float* dbih    = (const float*)d_in[16];
  const float* dbhh    = (const float*)d_in[17];
  const float* aWenc   = (const float*)d_in[18];
  const float* abenc   = (const float*)d_in[19];
  const float* aWdec   = (const float*)d_in[20];
  const float* abdec   = (const float*)d_in[21];
  const float* av      = (const float*)d_in[22];
  const float* avb     = (const float*)d_in[23];
  const float* lW      = (const float*)d_in[24];
  const float* lb      = (const float*)d_in[25];
  float* dout = (float*)d_out;

  char* ws = (char*)d_ws;
  size_t off = 0;
  auto alloc = [&](size_t bytes) {
    void* p = ws + off;
    off += (bytes + 255) & ~(size_t)255;
    return p;
  };
  unsigned short* xb      = (unsigned short*)alloc((size_t)4096 * 256 * 2);
  unsigned short* xeb     = (unsigned short*)alloc((size_t)2016 * 256 * 2);
  unsigned short* xpb_f   = (unsigned short*)alloc((size_t)4096 * G3_ * 2);
  unsigned short* xpb_b   = (unsigned short*)alloc((size_t)4096 * G3_ * 2);
  unsigned short* encb    = (unsigned short*)alloc((size_t)4096 * D2H_ * 2);
  unsigned short* encpb   = (unsigned short*)alloc((size_t)4096 * 512 * 2);
  unsigned short* encWA   = (unsigned short*)alloc((size_t)4096 * G3_ * 2);
  uint2*          EW2d    = (uint2*)alloc((size_t)32 * 64 * 768 * 8);
  float*          XE      = (float*)alloc((size_t)2016 * G3_ * 4);
  unsigned short* HAb     = (unsigned short*)alloc((size_t)2048 * G3_ * 2);
  unsigned short* lWb     = (unsigned short*)alloc((size_t)VO_ * G3_ * 2);
  uint2*          W2f     = (uint2*)alloc((size_t)196608 * 8);
  uint2*          W2b     = (uint2*)alloc((size_t)196608 * 8);
  uint2*          WH2     = (uint2*)alloc((size_t)196608 * 8);
  uint2*          WD2     = (uint2*)alloc((size_t)65536 * 8);
  unsigned short* dWihb   = (unsigned short*)alloc((size_t)G3_ * 1280 * 2);
  unsigned short* aWencb  = (unsigned short*)alloc((size_t)512 * D2H_ * 2);
  unsigned short* eWihb_f = (unsigned short*)alloc((size_t)G3_ * 256 * 2);
  unsigned short* eWihb_b = (unsigned short*)alloc((size_t)G3_ * 256 * 2);

  // init + conversions
  k_init<<<192, 256, 0, stream>>>(HAb + (size_t)2016 * G3_);
  k_cvt_multi<<<1600, 256, 0, stream>>>(dWih, dWihb, aWenc, aWencb,
                                        eWih_f, eWihb_f, eWih_b, eWihb_b);
  k_cvt_w2<<<2560, 256, 0, stream>>>(eWhh_f, W2f, eWhh_b, W2b, dWhh, WH2, aWdec, WD2);
  k_cvt_bf16<<<24000, 256, 0, stream>>>(lW, lWb, VO_ * G3_ / 8);

  // embeddings
  k_gather_xb<<<512, 256, 0, stream>>>(inp, emb_inp, xb);
  k_gather_xeb<<<252, 256, 0, stream>>>(outi, emb_out, xeb);

  // xp = x @ eWih^T + ebih  (bf16 out)
  {
    dim3 g(12, 32);
    k_bgemm<1><<<g, 256, 0, stream>>>(xb, 256, eWihb_f, 256, ebih_f, xpb_f, G3_, 4096, G3_, 256);
    k_bgemm<1><<<g, 256, 0, stream>>>(xb, 256, eWihb_b, 256, ebih_b, xpb_b, G3_, 4096, G3_, 256);
  }

  // encoder
  k_encoder<<<64, 1024, 0, stream>>>(xpb_f, xpb_b, W2f, ebhh_f, W2b, ebhh_b, encb);

  // enc_proj (bias folded into decoder dp)
  {
    dim3 g(4, 32);
    k_bgemm<1><<<g, 256, 0, stream>>>(encb, D2H_, aWencb, D2H_, nullptr, encpb, 512, 4096, 512, D2H_);
  }
  // encWA = enc @ dWih_a^T  [4096][1536] bf16, then t-pair/col-pair repack
  {
    dim3 g(12, 32);
    k_bgemm<1><<<g, 256, 0, stream>>>(encb, D2H_, dWihb + 256, 1280, nullptr, encWA, G3_, 4096, G3_, D2H_);
  }
  k_packT2<<<6144, 256, 0, stream>>>(encWA, EW2d);

  // XE = xe @ dWih_e^T + dbih (f32 out)
  {
    dim3 g(12, 16);
    k_bgemm<0><<<g, 256, 0, stream>>>(xeb, 256, dWihb, 1280, dbih, XE, G3_, 2016, G3_, 256);
  }

  // decoder
  k_decoder<<<32, 1024, 0, stream>>>(inp, encb, encpb, XE, EW2d, WH2, WD2,
                                     dsW, dsb, dbhh, abdec, abenc, av, avb, HAb);

  // logits
  {
    dim3 g(250, 16);
    k_bgemm<3><<<g, 256, 0, stream>>>(HAb, G3_, lWb, G3_, lb, dout, 0, 2016, VO_, G3_);
  }
  k_first<<<4000, 256, 0, stream>>>(dout);
}

// Round 8
// 13635.706 us; speedup vs baseline: 1.0068x; 1.0068x over previous
//
#include <hip/hip_runtime.h>
#include <math.h>
#include <stdint.h>

#define B_   32
#define TI_  128
#define TO_  64
#define E_   256
#define H_   512
#define A_   512
#define VO_  32000
#define G3_  1536   // 3H
#define D2H_ 1024   // 2H

using short8 = __attribute__((ext_vector_type(8))) short;
using f32x4  = __attribute__((ext_vector_type(4))) float;
typedef __attribute__((ext_vector_type(2))) float floatx2;
typedef __attribute__((ext_vector_type(2))) __bf16 bf16x2_t;

__device__ __forceinline__ unsigned short f2bf(float x) {
  uint32_t u = __builtin_bit_cast(uint32_t, x);
  uint32_t r = (u + 0x7fffu + ((u >> 16) & 1u)) >> 16;
  return (unsigned short)r;
}
__device__ __forceinline__ uint32_t pack2(float lo, float hi) {
  return (uint32_t)f2bf(lo) | ((uint32_t)f2bf(hi) << 16);
}
__device__ __forceinline__ float bflo(uint32_t u) { return __builtin_bit_cast(float, u << 16); }
__device__ __forceinline__ float bfhi(uint32_t u) { return __builtin_bit_cast(float, u & 0xffff0000u); }

#if __has_builtin(__builtin_amdgcn_fdot2_f32_bf16)
__device__ __forceinline__ float dot2bf(uint32_t a, uint32_t b, float c) {
  return __builtin_amdgcn_fdot2_f32_bf16(__builtin_bit_cast(bf16x2_t, a),
                                         __builtin_bit_cast(bf16x2_t, b), c, false);
}
#else
__device__ __forceinline__ float dot2bf(uint32_t a, uint32_t b, float c) {
  return fmaf(bfhi(a), bfhi(b), fmaf(bflo(a), bflo(b), c));
}
#endif

// ---- fp8 e4m3 pack/unpack (hw cvt when available; word-select must be literal) ----
#if __has_builtin(__builtin_amdgcn_cvt_pk_fp8_f32) && __has_builtin(__builtin_amdgcn_cvt_pk_f32_fp8)
__device__ __forceinline__ uint32_t pk4_e4m3(float a, float b, float c, float d) {
  int v = 0;
  v = __builtin_amdgcn_cvt_pk_fp8_f32(a, b, v, false);
  v = __builtin_amdgcn_cvt_pk_fp8_f32(c, d, v, true);
  return (uint32_t)v;
}
template <bool HI>
__device__ __forceinline__ floatx2 up2_e4m3(uint32_t u) {
  return __builtin_amdgcn_cvt_pk_f32_fp8((int)u, HI);
}
#else
__device__ __forceinline__ uint32_t enc1_e4m3(float x) {
  float ax = fabsf(x);
  uint32_t s = (x < 0.f) ? 0x80u : 0u;
  if (!(ax > 0.0078125f)) return s;
  ax = fminf(ax, 448.f);
  uint32_t u = __builtin_bit_cast(uint32_t, ax);
  uint32_t lsb = (u >> 20) & 1u;
  u += 0x7FFFFu + lsb;
  int e = (int)((u >> 23) & 0xFF) - 127;
  if (e < -6) return s;
  uint32_t m = (u >> 20) & 7u;
  uint32_t ee = (uint32_t)(e + 7);
  if (ee > 15u || (ee == 15u && m == 7u)) { ee = 15u; m = 6u; }
  return s | (ee << 3) | m;
}
__device__ __forceinline__ float dec1_e4m3(uint32_t b) {
  uint32_t e = (b >> 3) & 15u, m = b & 7u;
  float r;
  if (e) r = __builtin_bit_cast(float, ((e + 120u) << 23) | (m << 20));
  else   r = (float)m * 0.001953125f;
  return (b & 0x80u) ? -r : r;
}
__device__ __forceinline__ uint32_t pk4_e4m3(float a, float b, float c, float d) {
  return enc1_e4m3(a) | (enc1_e4m3(b) << 8) | (enc1_e4m3(c) << 16) | (enc1_e4m3(d) << 24);
}
template <bool HI>
__device__ __forceinline__ floatx2 up2_e4m3(uint32_t u) {
  uint32_t w = HI ? (u >> 16) : u;
  floatx2 r = { dec1_e4m3(w & 0xffu), dec1_e4m3((w >> 8) & 0xffu) };
  return r;
}
#endif

__device__ __forceinline__ float sigf(float x) {
  return __builtin_amdgcn_rcpf(1.f + __expf(-x));
}
__device__ __forceinline__ float tanhf_(float x) {
  return fmaf(-2.f, __builtin_amdgcn_rcpf(1.f + __expf(2.f * x)), 1.f);
}

// ---------------- init: zero HAb tail rows ----------------------------------
__global__ __launch_bounds__(256) void k_init(unsigned short* __restrict__ tail) {
  int i = blockIdx.x * 256 + threadIdx.x;
  if (i < 32 * G3_) tail[i] = 0;
}

// ---------------- f32 -> bf16 row-major (8 elems/thread) --------------------
__global__ __launch_bounds__(256) void k_cvt_bf16(const float* __restrict__ in,
                                                  unsigned short* __restrict__ out, int n8) {
  int i = blockIdx.x * 256 + threadIdx.x;
  if (i >= n8) return;
  float4 a = ((const float4*)in)[2 * i];
  float4 b = ((const float4*)in)[2 * i + 1];
  uint4 o = { pack2(a.x, a.y), pack2(a.z, a.w), pack2(b.x, b.y), pack2(b.z, b.w) };
  ((uint4*)out)[i] = o;
}

// row-major bf16 conversions for MFMA GEMM operands
__global__ __launch_bounds__(256) void k_cvt_multi(
    const float* __restrict__ i0, unsigned short* __restrict__ o0,   // dWih  245760 u8
    const float* __restrict__ i1, unsigned short* __restrict__ o1,   // aWenc  65536
    const float* __restrict__ i2, unsigned short* __restrict__ o2,   // eWih_f 49152
    const float* __restrict__ i3, unsigned short* __restrict__ o3) { // eWih_b 49152
  int u = blockIdx.x * 256 + threadIdx.x;
  const float* in; unsigned short* out; int lu;
  if      (u < 245760) { in = i0; out = o0; lu = u; }
  else if (u < 311296) { in = i1; out = o1; lu = u - 245760; }
  else if (u < 360448) { in = i2; out = o2; lu = u - 311296; }
  else if (u < 409600) { in = i3; out = o3; lu = u - 360448; }
  else return;
  float4 a = ((const float4*)in)[2 * lu];
  float4 b = ((const float4*)in)[2 * lu + 1];
  uint4 o = { pack2(a.x, a.y), pack2(a.z, a.w), pack2(b.x, b.y), pack2(b.z, b.w) };
  ((uint4*)out)[lu] = o;
}

// W2 layout: uint2[kp][P], entry [kp][gg*256+cg] = { pack(W[gg*512+2cg][2kp..]),
//                                                    pack(W[gg*512+2cg+1][2kp..]) }
__global__ __launch_bounds__(256) void k_cvt_w2(
    const float* __restrict__ i0, uint2* __restrict__ o0,   // eWhh_f 196608
    const float* __restrict__ i1, uint2* __restrict__ o1,   // eWhh_b 196608
    const float* __restrict__ i2, uint2* __restrict__ o2,   // dWhh   196608
    const float* __restrict__ i3, uint2* __restrict__ o3) { // aWdec   65536 (P=256)
  int u = blockIdx.x * 256 + threadIdx.x;
  const float* in; uint2* out; int lu, perkp;
  if      (u < 196608) { in = i0; out = o0; lu = u;          perkp = 768; }
  else if (u < 393216) { in = i1; out = o1; lu = u - 196608; perkp = 768; }
  else if (u < 589824) { in = i2; out = o2; lu = u - 393216; perkp = 768; }
  else if (u < 655360) { in = i3; out = o3; lu = u - 589824; perkp = 256; }
  else return;
  int kp = lu / perkp, rest = lu % perkp;
  int gg = rest >> 8, cg = rest & 255;
  int row0 = gg * 512 + 2 * cg;
  const float* p0 = in + (size_t)row0 * 512 + 2 * kp;
  const float* p1 = p0 + 512;
  uint2 o = { pack2(p0[0], p0[1]), pack2(p1[0], p1[1]) };
  out[lu] = o;
}

// EW8 (fp8): encWA bf16 [4096][1536] -> uint2 [((b*4+kq)*8+tq)*768 + gate*256 + cg]
//  .x = 4 fp8 of encWA[b, t=kq*32+tq*4+{0..3}, col gate*512+2cg], .y = col+1
__global__ __launch_bounds__(256) void k_packEW8(const unsigned short* __restrict__ encWA,
                                                 uint2* __restrict__ EW8) {
  int idx = blockIdx.x * 256 + threadIdx.x;
  if (idx >= 786432) return;
  int cg = idx & 255;
  int gate = (idx >> 8) % 3;
  int rest = idx / 768;
  int tq = rest & 7, kq = (rest >> 3) & 3, b = rest >> 5;
  int tbase = kq * 32 + tq * 4;
  int col = gate * 512 + 2 * cg;
  float vx[4], vy[4];
#pragma unroll
  for (int u = 0; u < 4; ++u) {
    size_t r = ((size_t)(b * 128 + tbase + u)) * 1536 + col;
    vx[u] = bflo((uint32_t)encWA[r]);
    vy[u] = bflo((uint32_t)encWA[r + 1]);
  }
  uint2 o = { pk4_e4m3(vx[0], vx[1], vx[2], vx[3]),
              pk4_e4m3(vy[0], vy[1], vy[2], vy[3]) };
  EW8[idx] = o;
}

// ---------------- embedding gathers (bf16 out) ------------------------------
__global__ __launch_bounds__(256) void k_gather_xb(const int* __restrict__ inp,
                                                   const float* __restrict__ emb,
                                                   unsigned short* __restrict__ xb) {
  int idx = blockIdx.x * 256 + threadIdx.x;
  if (idx >= 4096 * 32) return;
  int row = idx >> 5, e8 = idx & 31;
  int tok = inp[row];
  const float4* s = (const float4*)(emb + (size_t)tok * E_ + e8 * 8);
  float4 a = s[0], b = s[1];
  uint4 o = { pack2(a.x, a.y), pack2(a.z, a.w), pack2(b.x, b.y), pack2(b.z, b.w) };
  ((uint4*)xb)[idx] = o;
}

__global__ __launch_bounds__(256) void k_gather_xeb(const int* __restrict__ outi,
                                                    const float* __restrict__ emb,
                                                    unsigned short* __restrict__ xeb) {
  int idx = blockIdx.x * 256 + threadIdx.x;
  if (idx >= 2016 * 32) return;
  int row = idx >> 5, e8 = idx & 31;
  int i = row >> 5, b = row & 31;
  int tok = outi[b * TO_ + i];
  const float4* s = (const float4*)(emb + (size_t)tok * E_ + e8 * 8);
  float4 a = s[0], bb = s[1];
  uint4 o = { pack2(a.x, a.y), pack2(a.z, a.w), pack2(bb.x, bb.y), pack2(bb.z, bb.w) };
  ((uint4*)xeb)[idx] = o;
}

__global__ __launch_bounds__(256) void k_first(float* __restrict__ dout) {
  int idx = blockIdx.x * 256 + threadIdx.x;
  if (idx >= B_ * VO_) return;
  int b = idx / VO_, v = idx % VO_;
  dout[(size_t)b * TO_ * VO_ + v] = (v == 1) ? 0.f : -20.72326583694641f;
}

// ---------------- generic bf16 MFMA GEMM (m97 structure) ---------------------
template <int MODE>
__global__ __launch_bounds__(256) void k_bgemm(
    const unsigned short* __restrict__ A, int lda,
    const unsigned short* __restrict__ Bt, int ldb,
    const float* __restrict__ bias,
    void* __restrict__ Cv, int ldc, int M, int N, int K) {
  __shared__ alignas(16) unsigned short As[128 * 32];
  __shared__ alignas(16) unsigned short Bs[128 * 32];
  const int tid = threadIdx.x;
  const int wave = tid >> 6, lane = tid & 63;
  const int m0 = blockIdx.y * 128, n0 = blockIdx.x * 128;
  const int wr = wave >> 1, wc = wave & 1;

  f32x4 acc[4][4];
#pragma unroll
  for (int i = 0; i < 4; ++i)
#pragma unroll
    for (int j = 0; j < 4; ++j) acc[i][j] = (f32x4){0.f, 0.f, 0.f, 0.f};

  const int srow = tid >> 2;
  const int sbyte = (tid & 3) * 16;
  const int fr = lane & 15;
  const int fkb = (lane >> 4) * 16;

  for (int k0 = 0; k0 < K; k0 += 32) {
#pragma unroll
    for (int rd = 0; rd < 2; ++rd) {
      int row = rd * 64 + srow;
      int ra = min(m0 + row, M - 1);
      const char* ga = (const char*)(A + (size_t)ra * lda + k0) + sbyte;
      const char* gb = (const char*)(Bt + (size_t)(n0 + row) * ldb + k0) + sbyte;
      __builtin_amdgcn_global_load_lds(
          (const __attribute__((address_space(1))) uint32_t*)ga,
          (__attribute__((address_space(3))) uint32_t*)((char*)As + rd * 4096 + wave * 1024),
          16, 0, 0);
      __builtin_amdgcn_global_load_lds(
          (const __attribute__((address_space(1))) uint32_t*)gb,
          (__attribute__((address_space(3))) uint32_t*)((char*)Bs + rd * 4096 + wave * 1024),
          16, 0, 0);
    }
    __syncthreads();

    short8 af[4], bf[4];
#pragma unroll
    for (int i = 0; i < 4; ++i) {
      int ar = wr * 64 + i * 16 + fr;
      int bc = wc * 64 + i * 16 + fr;
      af[i] = *(const short8*)((const char*)As + ar * 64 + fkb);
      bf[i] = *(const short8*)((const char*)Bs + bc * 64 + fkb);
    }
#pragma unroll
    for (int i = 0; i < 4; ++i)
#pragma unroll
      for (int j = 0; j < 4; ++j)
        acc[i][j] = __builtin_amdgcn_mfma_f32_16x16x32_bf16(af[i], bf[j], acc[i][j], 0, 0, 0);
    __syncthreads();
  }

  const int crow = (lane >> 4) * 4, ccol = lane & 15;
#pragma unroll
  for (int i = 0; i < 4; ++i) {
#pragma unroll
    for (int r = 0; r < 4; ++r) {
      int m = m0 + wr * 64 + i * 16 + crow + r;
      if (m >= M) continue;
#pragma unroll
      for (int j = 0; j < 4; ++j) {
        int n = n0 + wc * 64 + j * 16 + ccol;
        float v = acc[i][j][r] + (bias ? bias[n] : 0.f);
        if (MODE == 0) {
          ((float*)Cv)[(size_t)m * ldc + n] = v;
        } else if (MODE == 1) {
          ((unsigned short*)Cv)[(size_t)m * ldc + n] = f2bf(v);
        } else {
          int bb = m & 31, st = m >> 5;
          ((float*)Cv)[((size_t)bb * TO_ + st + 1) * VO_ + n] = v;
        }
      }
    }
  }
}

// ---------------- persistent encoder: 32 blocks, 2 chains each ---------------
// dir = bid>>4, chains b0=2g, b1=2g+1 (g=bid&15). cg=tid>>2, kq=tid&3.
// Each weight uint2 load feeds 12 dot2 (2 chains x 2 cols x 3 gates).
__global__ __launch_bounds__(1024, 4) void k_encoder(
    const unsigned short* __restrict__ xpb_f, const unsigned short* __restrict__ xpb_b,
    const uint2* __restrict__ W2f, const float* __restrict__ bhh_f,
    const uint2* __restrict__ W2b, const float* __restrict__ bhh_b,
    unsigned short* __restrict__ encb) {
  __shared__ float hf0s[512], hf1s[512];
  __shared__ uint32_t hp0[260], hp1[260];
  const int bid = blockIdx.x;
  const int dir = bid >> 4, g = bid & 15;
  const int b0 = 2 * g, b1 = 2 * g + 1;
  const unsigned short* xpb = dir ? xpb_b : xpb_f;
  const uint2* W2 = dir ? W2b : W2f;
  const float* bhh = dir ? bhh_b : bhh_f;
  const int tid = threadIdx.x;
  const int cg = tid >> 2, kq = tid & 3;
  const int c0 = 2 * cg, c1 = c0 + 1;

  if (tid < 512) { hf0s[tid] = 0.f; hf1s[tid] = 0.f; }
  if (tid < 260) { hp0[tid] = 0u; hp1[tid] = 0u; }
  float br0 = 0, br1 = 0, bz0 = 0, bz1 = 0, bn0 = 0, bn1 = 0;
  if (kq == 0) {
    br0 = bhh[c0]; br1 = bhh[c1];
    bz0 = bhh[512 + c0]; bz1 = bhh[512 + c1];
    bn0 = bhh[1024 + c0]; bn1 = bhh[1024 + c1];
  }
  const uint2* wbase = W2 + (size_t)(kq * 64) * 768 + cg;
  const uint32_t* hq0 = hp0 + kq * 65;
  const uint32_t* hq1 = hp1 + kq * 65;
  uint32_t* encw = (uint32_t*)encb;
  __syncthreads();

  for (int t = 0; t < TI_; ++t) {
    const int tt = dir ? (TI_ - 1 - t) : t;
    float fr0 = 0, fr1 = 0, fz0 = 0, fz1 = 0, fn0 = 0, fn1 = 0;   // chain b0
    float gr0 = 0, gr1 = 0, gz0 = 0, gz1 = 0, gn0 = 0, gn1 = 0;   // chain b1
#pragma unroll
    for (int c = 0; c < 16; ++c) {
#pragma unroll
      for (int j = 0; j < 4; ++j) {
        const uint2* wp = wbase + (size_t)(c * 4 + j) * 768;
        uint2 wr = wp[0];
        uint2 wz = wp[256];
        uint2 wn = wp[512];
        uint32_t h0 = hq0[c * 4 + j];
        uint32_t h1 = hq1[c * 4 + j];
        fr0 = dot2bf(h0, wr.x, fr0); fr1 = dot2bf(h0, wr.y, fr1);
        gr0 = dot2bf(h1, wr.x, gr0); gr1 = dot2bf(h1, wr.y, gr1);
        fz0 = dot2bf(h0, wz.x, fz0); fz1 = dot2bf(h0, wz.y, fz1);
        gz0 = dot2bf(h1, wz.x, gz0); gz1 = dot2bf(h1, wz.y, gz1);
        fn0 = dot2bf(h0, wn.x, fn0); fn1 = dot2bf(h0, wn.y, fn1);
        gn0 = dot2bf(h1, wn.x, gn0); gn1 = dot2bf(h1, wn.y, gn1);
      }
    }
    fr0 += __shfl_xor(fr0, 1); fr0 += __shfl_xor(fr0, 2);
    fr1 += __shfl_xor(fr1, 1); fr1 += __shfl_xor(fr1, 2);
    fz0 += __shfl_xor(fz0, 1); fz0 += __shfl_xor(fz0, 2);
    fz1 += __shfl_xor(fz1, 1); fz1 += __shfl_xor(fz1, 2);
    fn0 += __shfl_xor(fn0, 1); fn0 += __shfl_xor(fn0, 2);
    fn1 += __shfl_xor(fn1, 1); fn1 += __shfl_xor(fn1, 2);
    gr0 += __shfl_xor(gr0, 1); gr0 += __shfl_xor(gr0, 2);
    gr1 += __shfl_xor(gr1, 1); gr1 += __shfl_xor(gr1, 2);
    gz0 += __shfl_xor(gz0, 1); gz0 += __shfl_xor(gz0, 2);
    gz1 += __shfl_xor(gz1, 1); gz1 += __shfl_xor(gz1, 2);
    gn0 += __shfl_xor(gn0, 1); gn0 += __shfl_xor(gn0, 2);
    gn1 += __shfl_xor(gn1, 1); gn1 += __shfl_xor(gn1, 2);

    float h00 = 0.f, h01 = 0.f, h10 = 0.f, h11 = 0.f;
    if (kq == 0) {
      const uint32_t* x0 = (const uint32_t*)(xpb + (size_t)(b0 * 128 + tt) * G3_);
      const uint32_t* x1 = (const uint32_t*)(xpb + (size_t)(b1 * 128 + tt) * G3_);
      uint32_t u0r = x0[cg], u0z = x0[256 + cg], u0n = x0[512 + cg];
      uint32_t u1r = x1[cg], u1z = x1[256 + cg], u1n = x1[512 + cg];
      {
        float r0 = sigf(bflo(u0r) + fr0 + br0);
        float r1 = sigf(bfhi(u0r) + fr1 + br1);
        float z0 = sigf(bflo(u0z) + fz0 + bz0);
        float z1 = sigf(bfhi(u0z) + fz1 + bz1);
        float n0 = tanhf_(bflo(u0n) + r0 * (fn0 + bn0));
        float n1 = tanhf_(bfhi(u0n) + r1 * (fn1 + bn1));
        h00 = (1.f - z0) * n0 + z0 * hf0s[c0];
        h01 = (1.f - z1) * n1 + z1 * hf0s[c1];
        encw[(size_t)(b0 * 128 + tt) * 512 + dir * 256 + cg] = pack2(h00, h01);
      }
      {
        float r0 = sigf(bflo(u1r) + gr0 + br0);
        float r1 = sigf(bfhi(u1r) + gr1 + br1);
        float z0 = sigf(bflo(u1z) + gz0 + bz0);
        float z1 = sigf(bfhi(u1z) + gz1 + bz1);
        float n0 = tanhf_(bflo(u1n) + r0 * (gn0 + bn0));
        float n1 = tanhf_(bfhi(u1n) + r1 * (gn1 + bn1));
        h10 = (1.f - z0) * n0 + z0 * hf1s[c0];
        h11 = (1.f - z1) * n1 + z1 * hf1s[c1];
        encw[(size_t)(b1 * 128 + tt) * 512 + dir * 256 + cg] = pack2(h10, h11);
      }
    }
    __syncthreads();
    if (kq == 0) {
      hf0s[c0] = h00; hf0s[c1] = h01;
      hf1s[c0] = h10; hf1s[c1] = h11;
      hp0[cg + (cg >> 6)] = pack2(h00, h01);
      hp1[cg + (cg >> 6)] = pack2(h10, h11);
    }
    __syncthreads();
  }
}

// ---------------- persistent decoder: 32 blocks (1 chain each) ---------------
__global__ __launch_bounds__(1024, 4) void k_decoder(
    const int* __restrict__ inp,
    const unsigned short* __restrict__ encb,
    const unsigned short* __restrict__ encpb,
    const float* __restrict__ XE,
    const uint2* __restrict__ EW8,     // fp8: [((b*4+kq)*8+tq)*768 + gate*256 + cg]
    const uint2* __restrict__ WH2,     // [kp][gg*256+cg]
    const uint2* __restrict__ WD2,     // [kp][cg]
    const float* __restrict__ dsW, const float* __restrict__ dsb,
    const float* __restrict__ dbhh,
    const float* __restrict__ abdec, const float* __restrict__ abenc,
    const float* __restrict__ av, const float* __restrict__ avb,
    unsigned short* __restrict__ HAb) {
  __shared__ uint32_t encp_s[128 * 257];   // 131.6 KB, padded
  __shared__ uint32_t hb2p[260];
  __shared__ float hf[512];
  __shared__ float pr[128];
  __shared__ float prp[132];
  __shared__ float sc[128];
  __shared__ float msk[128];
  __shared__ float dp[512];
  __shared__ float vavf[512];
  __shared__ float red[1024];
  __shared__ float red2[1024];
  __shared__ float dpx[4];
  const int b = blockIdx.x, tid = threadIdx.x;
  const int cg = tid >> 2, kq = tid & 3;
  const int c0 = 2 * cg, c1 = c0 + 1;
  const uint32_t* hq = hb2p + kq * 65;

  float db_r0 = 0, db_r1 = 0, db_z0 = 0, db_z1 = 0, db_n0 = 0, db_n1 = 0;
  float adb0 = 0, adb1 = 0;
  if (kq == 0) {
    db_r0 = dbhh[c0]; db_r1 = dbhh[c1];
    db_z0 = dbhh[512 + c0]; db_z1 = dbhh[512 + c1];
    db_n0 = dbhh[1024 + c0]; db_n1 = dbhh[1024 + c1];
    adb0 = abdec[c0] + abenc[c0];
    adb1 = abdec[c1] + abenc[c1];
  }
  const float avb0 = avb[0];

  // stage enc_proj into padded LDS (once)
  {
    const uint32_t* epg = (const uint32_t*)(encpb + (size_t)b * 128 * 512);
#pragma unroll
    for (int i = 0; i < 32; ++i) {
      int u = tid + i * 1024;
      encp_s[(u >> 8) * 257 + (u & 255)] = epg[u];
    }
  }
  if (tid < 128) msk[tid] = (inp[b * TI_ + tid] != 0) ? 1.f : 0.f;
  if (tid < 512) vavf[tid] = av[tid];
  __syncthreads();
  if (tid < 64) {
    float s = msk[tid] + msk[tid + 64];
#pragma unroll
    for (int o = 32; o > 0; o >>= 1) s += __shfl_xor(s, o);
    if (tid == 0) dpx[0] = s;
  }
  __syncthreads();
  const int len = min((int)dpx[0], TI_ - 1);

  // ---- dec0 ----
  if (tid < 512) {
    uint32_t u = ((const uint32_t*)encb)[(size_t)(b * 128 + len) * 512 + tid];
    red[2 * tid] = bflo(u);
    red[2 * tid + 1] = bfhi(u);
  }
  __syncthreads();
  {
    const int col = tid >> 1, kh = tid & 1;
    const float4* w = (const float4*)(dsW + (size_t)col * D2H_ + kh * 512);
    float acc = 0.f;
#pragma unroll 8
    for (int k = 0; k < 128; ++k) {
      float4 l = ((const float4*)red)[kh * 128 + k];
      float4 q = w[k];
      acc = fmaf(l.x, q.x, fmaf(l.y, q.y, fmaf(l.z, q.z, fmaf(l.w, q.w, acc))));
    }
    acc += __shfl_xor(acc, 1);
    __syncthreads();
    if (kh == 0) hf[col] = acc + dsb[col];
    __syncthreads();
    if (tid < 256) hb2p[tid + (tid >> 6)] = pack2(hf[2 * tid], hf[2 * tid + 1]);
    __syncthreads();
  }

  auto attend = [&](int step) {
    // dp = h @ Wdec^T + bdec + benc
    {
      const uint2* wp = WD2 + (size_t)(kq * 64) * 256 + cg;
      float d0 = 0.f, d1 = 0.f;
#pragma unroll
      for (int c = 0; c < 16; ++c) {
#pragma unroll
        for (int j = 0; j < 4; ++j) {
          uint2 w = wp[(size_t)(c * 4 + j) * 256];
          uint32_t hv = hq[c * 4 + j];
          d0 = dot2bf(hv, w.x, d0);
          d1 = dot2bf(hv, w.y, d1);
        }
      }
      d0 += __shfl_xor(d0, 1); d0 += __shfl_xor(d0, 2);
      d1 += __shfl_xor(d1, 1); d1 += __shfl_xor(d1, 2);
      if (kq == 0) { dp[c0] = d0 + adb0; dp[c1] = d1 + adb1; }
    }
    __syncthreads();
    // scores from LDS encp_s
    {
      int t = tid >> 3, s8 = tid & 7;
      const uint32_t* ep = encp_s + t * 257 + s8;
      float s = 0.f;
#pragma unroll 4
      for (int i = 0; i < 32; ++i) {
        int j = s8 + 8 * i;
        uint32_t u = ep[8 * i];
        float2 d2 = *(const float2*)&dp[2 * j];
        float2 v2 = *(const float2*)&vavf[2 * j];
        s = fmaf(v2.x, tanhf_(bflo(u) + d2.x), s);
        s = fmaf(v2.y, tanhf_(bfhi(u) + d2.y), s);
      }
      s += __shfl_xor(s, 1);
      s += __shfl_xor(s, 2);
      s += __shfl_xor(s, 4);
      if (s8 == 0) sc[t] = s;
    }
    __syncthreads();
    if (tid < 128) sc[tid] = (msk[tid] > 0.f) ? sc[tid] + avb0 : -1e30f;
    __syncthreads();
    if (tid < 64) {
      float m = fmaxf(sc[tid], sc[tid + 64]);
#pragma unroll
      for (int o = 32; o > 0; o >>= 1) m = fmaxf(m, __shfl_xor(m, o));
      if (tid == 0) dpx[1] = m;
    }
    __syncthreads();
    if (tid < 128) pr[tid] = __expf(sc[tid] - dpx[1]);
    __syncthreads();
    if (tid < 64) {
      float s2 = pr[tid] + pr[tid + 64];
#pragma unroll
      for (int o = 32; o > 0; o >>= 1) s2 += __shfl_xor(s2, o);
      if (tid == 0) dpx[2] = s2;
    }
    __syncthreads();
    float inv = __builtin_amdgcn_rcpf(dpx[2]);
    if (tid < 128) {
      float v = pr[tid] * inv;
      pr[tid] = v;
      prp[tid + (tid >> 5)] = v;
    }
    __syncthreads();
    if (step >= 0) {
      // context = pr @ enc[b] -> HAb a-part
      const uint32_t* eb = (const uint32_t*)encb + (size_t)b * 128 * 512;
      int d = tid & 511, tq = tid >> 9;
      float x0 = 0.f, x1 = 0.f;
#pragma unroll 4
      for (int k = 0; k < 64; ++k) {
        int t = tq * 64 + k;
        float p = pr[t];
        uint32_t u = eb[(size_t)t * 512 + d];
        x0 = fmaf(p, bflo(u), x0);
        x1 = fmaf(p, bfhi(u), x1);
      }
      red[tid] = x0; red2[tid] = x1;
      __syncthreads();
      if (tid < 512) {
        x0 = red[tid] + red[tid + 512];
        x1 = red2[tid] + red2[tid + 512];
        uint32_t* hrow = (uint32_t*)(HAb + ((size_t)step * 32 + b) * G3_);
        hrow[256 + tid] = pack2(x0, x1);
      }
    }
    __syncthreads();
  };

  auto gru = [&](int i) {
    float xr0 = 0, xr1 = 0, xz0 = 0, xz1 = 0, xn0 = 0, xn1 = 0;
    // x-side: pr @ encW[b]  (fp8 stream)
    {
      const uint2* ep = EW8 + ((size_t)(b * 4 + kq) * 8) * 768 + cg;
      const float* pq = prp + kq * 33;
#pragma unroll
      for (int tq = 0; tq < 8; ++tq) {
        uint2 wr = ep[0];
        uint2 wz = ep[256];
        uint2 wn = ep[512];
        ep += 768;
        float p0 = pq[tq * 4], p1 = pq[tq * 4 + 1], p2 = pq[tq * 4 + 2], p3 = pq[tq * 4 + 3];
        floatx2 a0 = up2_e4m3<false>(wr.x), a1 = up2_e4m3<true>(wr.x);
        xr0 = fmaf(p0, a0.x, fmaf(p1, a0.y, fmaf(p2, a1.x, fmaf(p3, a1.y, xr0))));
        floatx2 b0_ = up2_e4m3<false>(wr.y), b1_ = up2_e4m3<true>(wr.y);
        xr1 = fmaf(p0, b0_.x, fmaf(p1, b0_.y, fmaf(p2, b1_.x, fmaf(p3, b1_.y, xr1))));
        floatx2 c0_ = up2_e4m3<false>(wz.x), c1_ = up2_e4m3<true>(wz.x);
        xz0 = fmaf(p0, c0_.x, fmaf(p1, c0_.y, fmaf(p2, c1_.x, fmaf(p3, c1_.y, xz0))));
        floatx2 d0_ = up2_e4m3<false>(wz.y), d1_ = up2_e4m3<true>(wz.y);
        xz1 = fmaf(p0, d0_.x, fmaf(p1, d0_.y, fmaf(p2, d1_.x, fmaf(p3, d1_.y, xz1))));
        floatx2 e0_ = up2_e4m3<false>(wn.x), e1_ = up2_e4m3<true>(wn.x);
        xn0 = fmaf(p0, e0_.x, fmaf(p1, e0_.y, fmaf(p2, e1_.x, fmaf(p3, e1_.y, xn0))));
        floatx2 f0_ = up2_e4m3<false>(wn.y), f1_ = up2_e4m3<true>(wn.y);
        xn1 = fmaf(p0, f0_.x, fmaf(p1, f0_.y, fmaf(p2, f1_.x, fmaf(p3, f1_.y, xn1))));
      }
    }
    float hr0 = 0, hr1 = 0, hz0 = 0, hz1 = 0, hn0 = 0, hn1 = 0;
    // h-side: h @ Whh^T  (bf16 uint2 stream)
    {
      const uint2* wp = WH2 + (size_t)(kq * 64) * 768 + cg;
#pragma unroll
      for (int c = 0; c < 16; ++c) {
#pragma unroll
        for (int j = 0; j < 4; ++j) {
          const uint2* w = wp + (size_t)(c * 4 + j) * 768;
          uint2 wr = w[0];
          uint2 wz = w[256];
          uint2 wn = w[512];
          uint32_t hv = hq[c * 4 + j];
          hr0 = dot2bf(hv, wr.x, hr0); hr1 = dot2bf(hv, wr.y, hr1);
          hz0 = dot2bf(hv, wz.x, hz0); hz1 = dot2bf(hv, wz.y, hz1);
          hn0 = dot2bf(hv, wn.x, hn0); hn1 = dot2bf(hv, wn.y, hn1);
        }
      }
    }
    float tr0 = xr0 + hr0; tr0 += __shfl_xor(tr0, 1); tr0 += __shfl_xor(tr0, 2);
    float tr1 = xr1 + hr1; tr1 += __shfl_xor(tr1, 1); tr1 += __shfl_xor(tr1, 2);
    float tz0 = xz0 + hz0; tz0 += __shfl_xor(tz0, 1); tz0 += __shfl_xor(tz0, 2);
    float tz1 = xz1 + hz1; tz1 += __shfl_xor(tz1, 1); tz1 += __shfl_xor(tz1, 2);
    xn0 += __shfl_xor(xn0, 1); xn0 += __shfl_xor(xn0, 2);
    xn1 += __shfl_xor(xn1, 1); xn1 += __shfl_xor(xn1, 2);
    hn0 += __shfl_xor(hn0, 1); hn0 += __shfl_xor(hn0, 2);
    hn1 += __shfl_xor(hn1, 1); hn1 += __shfl_xor(hn1, 2);

    float hnew0 = 0.f, hnew1 = 0.f;
    if (kq == 0) {
      const float* xrow = XE + ((size_t)i * 32 + b) * G3_;
      float r0 = sigf(xrow[c0] + tr0 + db_r0);
      float r1 = sigf(xrow[c1] + tr1 + db_r1);
      float z0 = sigf(xrow[512 + c0] + tz0 + db_z0);
      float z1 = sigf(xrow[512 + c1] + tz1 + db_z1);
      float n0 = tanhf_(xrow[1024 + c0] + xn0 + r0 * (hn0 + db_n0));
      float n1 = tanhf_(xrow[1024 + c1] + xn1 + r1 * (hn1 + db_n1));
      hnew0 = (1.f - z0) * n0 + z0 * hf[c0];
      hnew1 = (1.f - z1) * n1 + z1 * hf[c1];
      ((uint32_t*)(HAb + ((size_t)i * 32 + b) * G3_))[cg] = pack2(hnew0, hnew1);
    }
    __syncthreads();
    if (kq == 0) {
      hf[c0] = hnew0; hf[c1] = hnew1;
      hb2p[cg + (cg >> 6)] = pack2(hnew0, hnew1);
    }
    __syncthreads();
  };

  attend(-1);
  for (int i = 0; i < 63; ++i) {
    gru(i);
    attend(i);
  }
}

// ---------------- launch ------------------------------------------------------

extern "C" void kernel_launch(void* const* d_in, const int* in_sizes, int n_in,
                              void* d_out, int out_size, void* d_ws, size_t ws_size,
                              hipStream_t stream) {
  const int*   inp     = (const int*)d_in[0];
  const int*   outi    = (const int*)d_in[1];
  const float* emb_inp = (const float*)d_in[2];
  const float* emb_out = (const float*)d_in[3];
  const float* eWih_f  = (const float*)d_in[4];
  const float* eWhh_f  = (const float*)d_in[5];
  const float* ebih_f  = (const float*)d_in[6];
  const float* ebhh_f  = (const float*)d_in[7];
  const float* eWih_b  = (const float*)d_in[8];
  const float* eWhh_b  = (const float*)d_in[9];
  const float* ebih_b  = (const float*)d_in[10];
  const float* ebhh_b  = (const float*)d_in[11];
  const float* dsW     = (const float*)d_in[12];
  const float* dsb     = (const float*)d_in[13];
  const float* dWih    = (const float*)d_in[14];
  const float* dWhh    = (const float*)d_in[15];
  const float* dbih    = (const float*)d_in[16];
  const float* dbhh    = (const float*)d_in[17];
  const float* aWenc   = (const float*)d_in[18];
  const float* abenc   = (const float*)d_in[19];
  const float* aWdec   = (const float*)d_in[20];
  const float* abdec   = (const float*)d_in[21];
  const float* av      = (const float*)d_in[22];
  const float* avb     = (const float*)d_in[23];
  const float* lW      = (const float*)d_in[24];
  const float* lb      = (const float*)d_in[25];
  float* dout = (float*)d_out;

  char* ws = (char*)d_ws;
  size_t off = 0;
  auto alloc = [&](size_t bytes) {
    void* p = ws + off;
    off += (bytes + 255) & ~(size_t)255;
    return p;
  };
  unsigned short* xb      = (unsigned short*)alloc((size_t)4096 * 256 * 2);
  unsigned short* xeb     = (unsigned short*)alloc((size_t)2016 * 256 * 2);
  unsigned short* xpb_f   = (unsigned short*)alloc((size_t)4096 * G3_ * 2);
  unsigned short* xpb_b   = (unsigned short*)alloc((size_t)4096 * G3_ * 2);
  unsigned short* encb    = (unsigned short*)alloc((size_t)4096 * D2H_ * 2);
  unsigned short* encpb   = (unsigned short*)alloc((size_t)4096 * 512 * 2);
  unsigned short* encWA   = (unsigned short*)alloc((size_t)4096 * G3_ * 2);
  uint2*          EW8     = (uint2*)alloc((size_t)786432 * 8);
  float*          XE      = (float*)alloc((size_t)2016 * G3_ * 4);
  unsigned short* HAb     = (unsigned short*)alloc((size_t)2048 * G3_ * 2);
  unsigned short* lWb     = (unsigned short*)alloc((size_t)VO_ * G3_ * 2);
  uint2*          W2f     = (uint2*)alloc((size_t)196608 * 8);
  uint2*          W2b     = (uint2*)alloc((size_t)196608 * 8);
  uint2*          WH2     = (uint2*)alloc((size_t)196608 * 8);
  uint2*          WD2     = (uint2*)alloc((size_t)65536 * 8);
  unsigned short* dWihb   = (unsigned short*)alloc((size_t)G3_ * 1280 * 2);
  unsigned short* aWencb  = (unsigned short*)alloc((size_t)512 * D2H_ * 2);
  unsigned short* eWihb_f = (unsigned short*)alloc((size_t)G3_ * 256 * 2);
  unsigned short* eWihb_b = (unsigned short*)alloc((size_t)G3_ * 256 * 2);

  // init + conversions
  k_init<<<192, 256, 0, stream>>>(HAb + (size_t)2016 * G3_);
  k_cvt_multi<<<1600, 256, 0, stream>>>(dWih, dWihb, aWenc, aWencb,
                                        eWih_f, eWihb_f, eWih_b, eWihb_b);
  k_cvt_w2<<<2560, 256, 0, stream>>>(eWhh_f, W2f, eWhh_b, W2b, dWhh, WH2, aWdec, WD2);
  k_cvt_bf16<<<24000, 256, 0, stream>>>(lW, lWb, VO_ * G3_ / 8);

  // embeddings
  k_gather_xb<<<512, 256, 0, stream>>>(inp, emb_inp, xb);
  k_gather_xeb<<<252, 256, 0, stream>>>(outi, emb_out, xeb);

  // xp = x @ eWih^T + ebih  (bf16 out)
  {
    dim3 g(12, 32);
    k_bgemm<1><<<g, 256, 0, stream>>>(xb, 256, eWihb_f, 256, ebih_f, xpb_f, G3_, 4096, G3_, 256);
    k_bgemm<1><<<g, 256, 0, stream>>>(xb, 256, eWihb_b, 256, ebih_b, xpb_b, G3_, 4096, G3_, 256);
  }

  // encoder (32 blocks, 2 chains each)
  k_encoder<<<32, 1024, 0, stream>>>(xpb_f, xpb_b, W2f, ebhh_f, W2b, ebhh_b, encb);

  // enc_proj (bias folded into decoder dp)
  {
    dim3 g(4, 32);
    k_bgemm<1><<<g, 256, 0, stream>>>(encb, D2H_, aWencb, D2H_, nullptr, encpb, 512, 4096, 512, D2H_);
  }
  // encWA = enc @ dWih_a^T  [4096][1536] bf16, then fp8 repack
  {
    dim3 g(12, 32);
    k_bgemm<1><<<g, 256, 0, stream>>>(encb, D2H_, dWihb + 256, 1280, nullptr, encWA, G3_, 4096, G3_, D2H_);
  }
  k_packEW8<<<3072, 256, 0, stream>>>(encWA, EW8);

  // XE = xe @ dWih_e^T + dbih (f32 out)
  {
    dim3 g(12, 16);
    k_bgemm<0><<<g, 256, 0, stream>>>(xeb, 256, dWihb, 1280, dbih, XE, G3_, 2016, G3_, 256);
  }

  // decoder
  k_decoder<<<32, 1024, 0, stream>>>(inp, encb, encpb, XE, EW8, WH2, WD2,
                                     dsW, dsb, dbhh, abdec, abenc, av, avb, HAb);

  // logits
  {
    dim3 g(250, 16);
    k_bgemm<3><<<g, 256, 0, stream>>>(HAb, G3_, lWb, G3_, lb, dout, 0, 2016, VO_, G3_);
  }
  k_first<<<4000, 256, 0, stream>>>(dout);
}

// Round 9
// 12867.114 us; speedup vs baseline: 1.0669x; 1.0597x over previous
//
#include <hip/hip_runtime.h>
#include <math.h>
#include <stdint.h>

#define B_   32
#define TI_  128
#define TO_  64
#define E_   256
#define H_   512
#define A_   512
#define VO_  32000
#define G3_  1536   // 3H
#define D2H_ 1024   // 2H

using short8 = __attribute__((ext_vector_type(8))) short;
using f32x4  = __attribute__((ext_vector_type(4))) float;
typedef __attribute__((ext_vector_type(2))) float floatx2;
typedef __attribute__((ext_vector_type(2))) __bf16 bf16x2_t;

__device__ __forceinline__ unsigned short f2bf(float x) {
  uint32_t u = __builtin_bit_cast(uint32_t, x);
  uint32_t r = (u + 0x7fffu + ((u >> 16) & 1u)) >> 16;
  return (unsigned short)r;
}
__device__ __forceinline__ uint32_t pack2(float lo, float hi) {
  return (uint32_t)f2bf(lo) | ((uint32_t)f2bf(hi) << 16);
}
__device__ __forceinline__ float bflo(uint32_t u) { return __builtin_bit_cast(float, u << 16); }
__device__ __forceinline__ float bfhi(uint32_t u) { return __builtin_bit_cast(float, u & 0xffff0000u); }

#if __has_builtin(__builtin_amdgcn_fdot2_f32_bf16)
__device__ __forceinline__ float dot2bf(uint32_t a, uint32_t b, float c) {
  return __builtin_amdgcn_fdot2_f32_bf16(__builtin_bit_cast(bf16x2_t, a),
                                         __builtin_bit_cast(bf16x2_t, b), c, false);
}
#else
__device__ __forceinline__ float dot2bf(uint32_t a, uint32_t b, float c) {
  return fmaf(bfhi(a), bfhi(b), fmaf(bflo(a), bflo(b), c));
}
#endif

// ---- fp8 e4m3 pack/unpack (hw cvt when available; word-select must be literal) ----
#if __has_builtin(__builtin_amdgcn_cvt_pk_fp8_f32) && __has_builtin(__builtin_amdgcn_cvt_pk_f32_fp8)
__device__ __forceinline__ uint32_t pk4_e4m3(float a, float b, float c, float d) {
  int v = 0;
  v = __builtin_amdgcn_cvt_pk_fp8_f32(a, b, v, false);
  v = __builtin_amdgcn_cvt_pk_fp8_f32(c, d, v, true);
  return (uint32_t)v;
}
template <bool HI>
__device__ __forceinline__ floatx2 up2_e4m3(uint32_t u) {
  return __builtin_amdgcn_cvt_pk_f32_fp8((int)u, HI);
}
#else
__device__ __forceinline__ uint32_t enc1_e4m3(float x) {
  float ax = fabsf(x);
  uint32_t s = (x < 0.f) ? 0x80u : 0u;
  if (!(ax > 0.0078125f)) return s;
  ax = fminf(ax, 448.f);
  uint32_t u = __builtin_bit_cast(uint32_t, ax);
  uint32_t lsb = (u >> 20) & 1u;
  u += 0x7FFFFu + lsb;
  int e = (int)((u >> 23) & 0xFF) - 127;
  if (e < -6) return s;
  uint32_t m = (u >> 20) & 7u;
  uint32_t ee = (uint32_t)(e + 7);
  if (ee > 15u || (ee == 15u && m == 7u)) { ee = 15u; m = 6u; }
  return s | (ee << 3) | m;
}
__device__ __forceinline__ float dec1_e4m3(uint32_t b) {
  uint32_t e = (b >> 3) & 15u, m = b & 7u;
  float r;
  if (e) r = __builtin_bit_cast(float, ((e + 120u) << 23) | (m << 20));
  else   r = (float)m * 0.001953125f;
  return (b & 0x80u) ? -r : r;
}
__device__ __forceinline__ uint32_t pk4_e4m3(float a, float b, float c, float d) {
  return enc1_e4m3(a) | (enc1_e4m3(b) << 8) | (enc1_e4m3(c) << 16) | (enc1_e4m3(d) << 24);
}
template <bool HI>
__device__ __forceinline__ floatx2 up2_e4m3(uint32_t u) {
  uint32_t w = HI ? (u >> 16) : u;
  floatx2 r = { dec1_e4m3(w & 0xffu), dec1_e4m3((w >> 8) & 0xffu) };
  return r;
}
#endif

__device__ __forceinline__ float sigf(float x) {
  return __builtin_amdgcn_rcpf(1.f + __expf(-x));
}
__device__ __forceinline__ float tanhf_(float x) {
  return fmaf(-2.f, __builtin_amdgcn_rcpf(1.f + __expf(2.f * x)), 1.f);
}

// ---------------- init: zero HAb tail rows ----------------------------------
__global__ __launch_bounds__(256) void k_init(unsigned short* __restrict__ tail) {
  int i = blockIdx.x * 256 + threadIdx.x;
  if (i < 32 * G3_) tail[i] = 0;
}

// ---------------- f32 -> bf16 row-major (8 elems/thread) --------------------
__global__ __launch_bounds__(256) void k_cvt_bf16(const float* __restrict__ in,
                                                  unsigned short* __restrict__ out, int n8) {
  int i = blockIdx.x * 256 + threadIdx.x;
  if (i >= n8) return;
  float4 a = ((const float4*)in)[2 * i];
  float4 b = ((const float4*)in)[2 * i + 1];
  uint4 o = { pack2(a.x, a.y), pack2(a.z, a.w), pack2(b.x, b.y), pack2(b.z, b.w) };
  ((uint4*)out)[i] = o;
}

// row-major bf16 conversions for MFMA GEMM operands
__global__ __launch_bounds__(256) void k_cvt_multi(
    const float* __restrict__ i0, unsigned short* __restrict__ o0,   // dWih  245760 u8
    const float* __restrict__ i1, unsigned short* __restrict__ o1,   // aWenc  65536
    const float* __restrict__ i2, unsigned short* __restrict__ o2,   // eWih_f 49152
    const float* __restrict__ i3, unsigned short* __restrict__ o3) { // eWih_b 49152
  int u = blockIdx.x * 256 + threadIdx.x;
  const float* in; unsigned short* out; int lu;
  if      (u < 245760) { in = i0; out = o0; lu = u; }
  else if (u < 311296) { in = i1; out = o1; lu = u - 245760; }
  else if (u < 360448) { in = i2; out = o2; lu = u - 311296; }
  else if (u < 409600) { in = i3; out = o3; lu = u - 360448; }
  else return;
  float4 a = ((const float4*)in)[2 * lu];
  float4 b = ((const float4*)in)[2 * lu + 1];
  uint4 o = { pack2(a.x, a.y), pack2(a.z, a.w), pack2(b.x, b.y), pack2(b.z, b.w) };
  ((uint4*)out)[lu] = o;
}

// fp8 weight pack: f32 W[N][512] -> uint2 [k4][gg*256+cg]; entry = {4 fp8 of
// W[gg*512+2cg][4k4..4k4+3], same for row+1}. k4 in 0..127.
__global__ __launch_bounds__(256) void k_cvt_w8(
    const float* __restrict__ i0, uint2* __restrict__ o0,   // eWhh_f 98304
    const float* __restrict__ i1, uint2* __restrict__ o1,   // eWhh_b 98304
    const float* __restrict__ i2, uint2* __restrict__ o2,   // dWhh   98304
    const float* __restrict__ i3, uint2* __restrict__ o3) { // aWdec  32768 (per=256)
  int u = blockIdx.x * 256 + threadIdx.x;
  const float* in; uint2* out; int lu, per;
  if      (u < 98304)  { in = i0; out = o0; lu = u;          per = 768; }
  else if (u < 196608) { in = i1; out = o1; lu = u - 98304;  per = 768; }
  else if (u < 294912) { in = i2; out = o2; lu = u - 196608; per = 768; }
  else if (u < 327680) { in = i3; out = o3; lu = u - 294912; per = 256; }
  else return;
  int k4 = lu / per, rest = lu % per;
  int gg = rest >> 8, cg = rest & 255;
  int row0 = gg * 512 + 2 * cg;
  const float* p0 = in + (size_t)row0 * 512 + 4 * k4;
  const float* p1 = p0 + 512;
  uint2 o = { pk4_e4m3(p0[0], p0[1], p0[2], p0[3]),
              pk4_e4m3(p1[0], p1[1], p1[2], p1[3]) };
  out[lu] = o;
}

// EW8 (fp8): encWA bf16 [4096][1536] -> uint2 [((b*4+kq)*8+tq)*768 + gate*256 + cg]
__global__ __launch_bounds__(256) void k_packEW8(const unsigned short* __restrict__ encWA,
                                                 uint2* __restrict__ EW8) {
  int idx = blockIdx.x * 256 + threadIdx.x;
  if (idx >= 786432) return;
  int cg = idx & 255;
  int gate = (idx >> 8) % 3;
  int rest = idx / 768;
  int tq = rest & 7, kq = (rest >> 3) & 3, b = rest >> 5;
  int tbase = kq * 32 + tq * 4;
  int col = gate * 512 + 2 * cg;
  float vx[4], vy[4];
#pragma unroll
  for (int u = 0; u < 4; ++u) {
    size_t r = ((size_t)(b * 128 + tbase + u)) * 1536 + col;
    vx[u] = bflo((uint32_t)encWA[r]);
    vy[u] = bflo((uint32_t)encWA[r + 1]);
  }
  uint2 o = { pk4_e4m3(vx[0], vx[1], vx[2], vx[3]),
              pk4_e4m3(vy[0], vy[1], vy[2], vy[3]) };
  EW8[idx] = o;
}

// ---------------- embedding gathers (bf16 out) ------------------------------
__global__ __launch_bounds__(256) void k_gather_xb(const int* __restrict__ inp,
                                                   const float* __restrict__ emb,
                                                   unsigned short* __restrict__ xb) {
  int idx = blockIdx.x * 256 + threadIdx.x;
  if (idx >= 4096 * 32) return;
  int row = idx >> 5, e8 = idx & 31;
  int tok = inp[row];
  const float4* s = (const float4*)(emb + (size_t)tok * E_ + e8 * 8);
  float4 a = s[0], b = s[1];
  uint4 o = { pack2(a.x, a.y), pack2(a.z, a.w), pack2(b.x, b.y), pack2(b.z, b.w) };
  ((uint4*)xb)[idx] = o;
}

__global__ __launch_bounds__(256) void k_gather_xeb(const int* __restrict__ outi,
                                                    const float* __restrict__ emb,
                                                    unsigned short* __restrict__ xeb) {
  int idx = blockIdx.x * 256 + threadIdx.x;
  if (idx >= 2016 * 32) return;
  int row = idx >> 5, e8 = idx & 31;
  int i = row >> 5, b = row & 31;
  int tok = outi[b * TO_ + i];
  const float4* s = (const float4*)(emb + (size_t)tok * E_ + e8 * 8);
  float4 a = s[0], bb = s[1];
  uint4 o = { pack2(a.x, a.y), pack2(a.z, a.w), pack2(bb.x, bb.y), pack2(bb.z, bb.w) };
  ((uint4*)xeb)[idx] = o;
}

__global__ __launch_bounds__(256) void k_first(float* __restrict__ dout) {
  int idx = blockIdx.x * 256 + threadIdx.x;
  if (idx >= B_ * VO_) return;
  int b = idx / VO_, v = idx % VO_;
  dout[(size_t)b * TO_ * VO_ + v] = (v == 1) ? 0.f : -20.72326583694641f;
}

// ---------------- generic bf16 MFMA GEMM (m97 structure) ---------------------
template <int MODE>
__global__ __launch_bounds__(256) void k_bgemm(
    const unsigned short* __restrict__ A, int lda,
    const unsigned short* __restrict__ Bt, int ldb,
    const float* __restrict__ bias,
    void* __restrict__ Cv, int ldc, int M, int N, int K) {
  __shared__ alignas(16) unsigned short As[128 * 32];
  __shared__ alignas(16) unsigned short Bs[128 * 32];
  const int tid = threadIdx.x;
  const int wave = tid >> 6, lane = tid & 63;
  const int m0 = blockIdx.y * 128, n0 = blockIdx.x * 128;
  const int wr = wave >> 1, wc = wave & 1;

  f32x4 acc[4][4];
#pragma unroll
  for (int i = 0; i < 4; ++i)
#pragma unroll
    for (int j = 0; j < 4; ++j) acc[i][j] = (f32x4){0.f, 0.f, 0.f, 0.f};

  const int srow = tid >> 2;
  const int sbyte = (tid & 3) * 16;
  const int fr = lane & 15;
  const int fkb = (lane >> 4) * 16;

  for (int k0 = 0; k0 < K; k0 += 32) {
#pragma unroll
    for (int rd = 0; rd < 2; ++rd) {
      int row = rd * 64 + srow;
      int ra = min(m0 + row, M - 1);
      const char* ga = (const char*)(A + (size_t)ra * lda + k0) + sbyte;
      const char* gb = (const char*)(Bt + (size_t)(n0 + row) * ldb + k0) + sbyte;
      __builtin_amdgcn_global_load_lds(
          (const __attribute__((address_space(1))) uint32_t*)ga,
          (__attribute__((address_space(3))) uint32_t*)((char*)As + rd * 4096 + wave * 1024),
          16, 0, 0);
      __builtin_amdgcn_global_load_lds(
          (const __attribute__((address_space(1))) uint32_t*)gb,
          (__attribute__((address_space(3))) uint32_t*)((char*)Bs + rd * 4096 + wave * 1024),
          16, 0, 0);
    }
    __syncthreads();

    short8 af[4], bf[4];
#pragma unroll
    for (int i = 0; i < 4; ++i) {
      int ar = wr * 64 + i * 16 + fr;
      int bc = wc * 64 + i * 16 + fr;
      af[i] = *(const short8*)((const char*)As + ar * 64 + fkb);
      bf[i] = *(const short8*)((const char*)Bs + bc * 64 + fkb);
    }
#pragma unroll
    for (int i = 0; i < 4; ++i)
#pragma unroll
      for (int j = 0; j < 4; ++j)
        acc[i][j] = __builtin_amdgcn_mfma_f32_16x16x32_bf16(af[i], bf[j], acc[i][j], 0, 0, 0);
    __syncthreads();
  }

  const int crow = (lane >> 4) * 4, ccol = lane & 15;
#pragma unroll
  for (int i = 0; i < 4; ++i) {
#pragma unroll
    for (int r = 0; r < 4; ++r) {
      int m = m0 + wr * 64 + i * 16 + crow + r;
      if (m >= M) continue;
#pragma unroll
      for (int j = 0; j < 4; ++j) {
        int n = n0 + wc * 64 + j * 16 + ccol;
        float v = acc[i][j][r] + (bias ? bias[n] : 0.f);
        if (MODE == 0) {
          ((float*)Cv)[(size_t)m * ldc + n] = v;
        } else if (MODE == 1) {
          ((unsigned short*)Cv)[(size_t)m * ldc + n] = f2bf(v);
        } else {
          int bb = m & 31, st = m >> 5;
          ((float*)Cv)[((size_t)bb * TO_ + st + 1) * VO_ + n] = v;
        }
      }
    }
  }
}

// ---------------- persistent encoder: 32 blocks, 2 chains, fp8 weights ------
__global__ __launch_bounds__(1024, 4) void k_encoder(
    const unsigned short* __restrict__ xpb_f, const unsigned short* __restrict__ xpb_b,
    const uint2* __restrict__ W8f, const float* __restrict__ bhh_f,
    const uint2* __restrict__ W8b, const float* __restrict__ bhh_b,
    unsigned short* __restrict__ encb) {
  __shared__ float hf0s[512], hf1s[512];
  __shared__ uint32_t hp0[260], hp1[260];
  const int bid = blockIdx.x;
  const int dir = bid >> 4, g = bid & 15;
  const int b0 = 2 * g, b1 = 2 * g + 1;
  const unsigned short* xpb = dir ? xpb_b : xpb_f;
  const uint2* W8 = dir ? W8b : W8f;
  const float* bhh = dir ? bhh_b : bhh_f;
  const int tid = threadIdx.x;
  const int cg = tid >> 2, kq = tid & 3;
  const int c0 = 2 * cg, c1 = c0 + 1;

  if (tid < 512) { hf0s[tid] = 0.f; hf1s[tid] = 0.f; }
  if (tid < 260) { hp0[tid] = 0u; hp1[tid] = 0u; }
  float br0 = 0, br1 = 0, bz0 = 0, bz1 = 0, bn0 = 0, bn1 = 0;
  if (kq == 0) {
    br0 = bhh[c0]; br1 = bhh[c1];
    bz0 = bhh[512 + c0]; bz1 = bhh[512 + c1];
    bn0 = bhh[1024 + c0]; bn1 = bhh[1024 + c1];
  }
  const uint2* wbase = W8 + (size_t)(kq * 32) * 768 + cg;
  const uint32_t* hq0 = hp0 + kq * 65;
  const uint32_t* hq1 = hp1 + kq * 65;
  uint32_t* encw = (uint32_t*)encb;
  __syncthreads();

  for (int t = 0; t < TI_; ++t) {
    const int tt = dir ? (TI_ - 1 - t) : t;
    float fr0 = 0, fr1 = 0, fz0 = 0, fz1 = 0, fn0 = 0, fn1 = 0;   // chain b0
    float gr0 = 0, gr1 = 0, gz0 = 0, gz1 = 0, gn0 = 0, gn1 = 0;   // chain b1
#pragma unroll 8
    for (int c = 0; c < 32; ++c) {
      const uint2* w = wbase + (size_t)c * 768;
      uint2 wr = w[0];
      uint2 wz = w[256];
      uint2 wn = w[512];
      uint32_t h0a = hq0[2 * c], h0b = hq0[2 * c + 1];
      uint32_t h1a = hq1[2 * c], h1b = hq1[2 * c + 1];
      floatx2 lo, hi;
      lo = up2_e4m3<false>(wr.x); hi = up2_e4m3<true>(wr.x);
      fr0 = fmaf(bflo(h0a), lo.x, fmaf(bfhi(h0a), lo.y, fmaf(bflo(h0b), hi.x, fmaf(bfhi(h0b), hi.y, fr0))));
      gr0 = fmaf(bflo(h1a), lo.x, fmaf(bfhi(h1a), lo.y, fmaf(bflo(h1b), hi.x, fmaf(bfhi(h1b), hi.y, gr0))));
      lo = up2_e4m3<false>(wr.y); hi = up2_e4m3<true>(wr.y);
      fr1 = fmaf(bflo(h0a), lo.x, fmaf(bfhi(h0a), lo.y, fmaf(bflo(h0b), hi.x, fmaf(bfhi(h0b), hi.y, fr1))));
      gr1 = fmaf(bflo(h1a), lo.x, fmaf(bfhi(h1a), lo.y, fmaf(bflo(h1b), hi.x, fmaf(bfhi(h1b), hi.y, gr1))));
      lo = up2_e4m3<false>(wz.x); hi = up2_e4m3<true>(wz.x);
      fz0 = fmaf(bflo(h0a), lo.x, fmaf(bfhi(h0a), lo.y, fmaf(bflo(h0b), hi.x, fmaf(bfhi(h0b), hi.y, fz0))));
      gz0 = fmaf(bflo(h1a), lo.x, fmaf(bfhi(h1a), lo.y, fmaf(bflo(h1b), hi.x, fmaf(bfhi(h1b), hi.y, gz0))));
      lo = up2_e4m3<false>(wz.y); hi = up2_e4m3<true>(wz.y);
      fz1 = fmaf(bflo(h0a), lo.x, fmaf(bfhi(h0a), lo.y, fmaf(bflo(h0b), hi.x, fmaf(bfhi(h0b), hi.y, fz1))));
      gz1 = fmaf(bflo(h1a), lo.x, fmaf(bfhi(h1a), lo.y, fmaf(bflo(h1b), hi.x, fmaf(bfhi(h1b), hi.y, gz1))));
      lo = up2_e4m3<false>(wn.x); hi = up2_e4m3<true>(wn.x);
      fn0 = fmaf(bflo(h0a), lo.x, fmaf(bfhi(h0a), lo.y, fmaf(bflo(h0b), hi.x, fmaf(bfhi(h0b), hi.y, fn0))));
      gn0 = fmaf(bflo(h1a), lo.x, fmaf(bfhi(h1a), lo.y, fmaf(bflo(h1b), hi.x, fmaf(bfhi(h1b), hi.y, gn0))));
      lo = up2_e4m3<false>(wn.y); hi = up2_e4m3<true>(wn.y);
      fn1 = fmaf(bflo(h0a), lo.x, fmaf(bfhi(h0a), lo.y, fmaf(bflo(h0b), hi.x, fmaf(bfhi(h0b), hi.y, fn1))));
      gn1 = fmaf(bflo(h1a), lo.x, fmaf(bfhi(h1a), lo.y, fmaf(bflo(h1b), hi.x, fmaf(bfhi(h1b), hi.y, gn1))));
    }
    fr0 += __shfl_xor(fr0, 1); fr0 += __shfl_xor(fr0, 2);
    fr1 += __shfl_xor(fr1, 1); fr1 += __shfl_xor(fr1, 2);
    fz0 += __shfl_xor(fz0, 1); fz0 += __shfl_xor(fz0, 2);
    fz1 += __shfl_xor(fz1, 1); fz1 += __shfl_xor(fz1, 2);
    fn0 += __shfl_xor(fn0, 1); fn0 += __shfl_xor(fn0, 2);
    fn1 += __shfl_xor(fn1, 1); fn1 += __shfl_xor(fn1, 2);
    gr0 += __shfl_xor(gr0, 1); gr0 += __shfl_xor(gr0, 2);
    gr1 += __shfl_xor(gr1, 1); gr1 += __shfl_xor(gr1, 2);
    gz0 += __shfl_xor(gz0, 1); gz0 += __shfl_xor(gz0, 2);
    gz1 += __shfl_xor(gz1, 1); gz1 += __shfl_xor(gz1, 2);
    gn0 += __shfl_xor(gn0, 1); gn0 += __shfl_xor(gn0, 2);
    gn1 += __shfl_xor(gn1, 1); gn1 += __shfl_xor(gn1, 2);

    float h00 = 0.f, h01 = 0.f, h10 = 0.f, h11 = 0.f;
    if (kq == 0) {
      const uint32_t* x0 = (const uint32_t*)(xpb + (size_t)(b0 * 128 + tt) * G3_);
      const uint32_t* x1 = (const uint32_t*)(xpb + (size_t)(b1 * 128 + tt) * G3_);
      uint32_t u0r = x0[cg], u0z = x0[256 + cg], u0n = x0[512 + cg];
      uint32_t u1r = x1[cg], u1z = x1[256 + cg], u1n = x1[512 + cg];
      {
        float r0 = sigf(bflo(u0r) + fr0 + br0);
        float r1 = sigf(bfhi(u0r) + fr1 + br1);
        float z0 = sigf(bflo(u0z) + fz0 + bz0);
        float z1 = sigf(bfhi(u0z) + fz1 + bz1);
        float n0 = tanhf_(bflo(u0n) + r0 * (fn0 + bn0));
        float n1 = tanhf_(bfhi(u0n) + r1 * (fn1 + bn1));
        h00 = (1.f - z0) * n0 + z0 * hf0s[c0];
        h01 = (1.f - z1) * n1 + z1 * hf0s[c1];
        encw[(size_t)(b0 * 128 + tt) * 512 + dir * 256 + cg] = pack2(h00, h01);
      }
      {
        float r0 = sigf(bflo(u1r) + gr0 + br0);
        float r1 = sigf(bfhi(u1r) + gr1 + br1);
        float z0 = sigf(bflo(u1z) + gz0 + bz0);
        float z1 = sigf(bfhi(u1z) + gz1 + bz1);
        float n0 = tanhf_(bflo(u1n) + r0 * (gn0 + bn0));
        float n1 = tanhf_(bfhi(u1n) + r1 * (gn1 + bn1));
        h10 = (1.f - z0) * n0 + z0 * hf1s[c0];
        h11 = (1.f - z1) * n1 + z1 * hf1s[c1];
        encw[(size_t)(b1 * 128 + tt) * 512 + dir * 256 + cg] = pack2(h10, h11);
      }
    }
    __syncthreads();
    if (kq == 0) {
      hf0s[c0] = h00; hf0s[c1] = h01;
      hf1s[c0] = h10; hf1s[c1] = h11;
      hp0[cg + (cg >> 6)] = pack2(h00, h01);
      hp1[cg + (cg >> 6)] = pack2(h10, h11);
    }
    __syncthreads();
  }
}

// ---------------- persistent decoder: 32 blocks (1 chain), fp8 weights -------
__global__ __launch_bounds__(1024, 4) void k_decoder(
    const int* __restrict__ inp,
    const unsigned short* __restrict__ encb,
    const unsigned short* __restrict__ encpb,
    const float* __restrict__ XE,
    const uint2* __restrict__ EW8,     // fp8: [((b*4+kq)*8+tq)*768 + gate*256 + cg]
    const uint2* __restrict__ WH8,     // fp8: [k4][gg*256+cg]
    const uint2* __restrict__ WD8,     // fp8: [k4][cg]
    const float* __restrict__ dsW, const float* __restrict__ dsb,
    const float* __restrict__ dbhh,
    const float* __restrict__ abdec, const float* __restrict__ abenc,
    const float* __restrict__ av, const float* __restrict__ avb,
    unsigned short* __restrict__ HAb) {
  __shared__ uint32_t encp_s[128 * 264];   // stride 264: bank = 8t+s8, conflict-free
  __shared__ uint32_t hb2p[260];
  __shared__ float hf[512];
  __shared__ float pr[128];
  __shared__ float prp[132];
  __shared__ float sc[128];
  __shared__ float msk[128];
  __shared__ float dp[512];
  __shared__ float vavf[512];
  __shared__ float red[1024];
  __shared__ float red2[1024];
  __shared__ float dpx[4];
  const int b = blockIdx.x, tid = threadIdx.x;
  const int cg = tid >> 2, kq = tid & 3;
  const int c0 = 2 * cg, c1 = c0 + 1;
  const uint32_t* hq = hb2p + kq * 65;

  float db_r0 = 0, db_r1 = 0, db_z0 = 0, db_z1 = 0, db_n0 = 0, db_n1 = 0;
  float adb0 = 0, adb1 = 0;
  if (kq == 0) {
    db_r0 = dbhh[c0]; db_r1 = dbhh[c1];
    db_z0 = dbhh[512 + c0]; db_z1 = dbhh[512 + c1];
    db_n0 = dbhh[1024 + c0]; db_n1 = dbhh[1024 + c1];
    adb0 = abdec[c0] + abenc[c0];
    adb1 = abdec[c1] + abenc[c1];
  }
  const float avb0 = avb[0];

  // stage enc_proj into padded LDS (once)
  {
    const uint32_t* epg = (const uint32_t*)(encpb + (size_t)b * 128 * 512);
#pragma unroll
    for (int i = 0; i < 32; ++i) {
      int u = tid + i * 1024;
      encp_s[(u >> 8) * 264 + (u & 255)] = epg[u];
    }
  }
  if (tid < 128) msk[tid] = (inp[b * TI_ + tid] != 0) ? 1.f : 0.f;
  if (tid < 512) vavf[tid] = av[tid];
  __syncthreads();
  if (tid < 64) {
    float s = msk[tid] + msk[tid + 64];
#pragma unroll
    for (int o = 32; o > 0; o >>= 1) s += __shfl_xor(s, o);
    if (tid == 0) dpx[0] = s;
  }
  __syncthreads();
  const int len = min((int)dpx[0], TI_ - 1);

  // ---- dec0 ----
  if (tid < 512) {
    uint32_t u = ((const uint32_t*)encb)[(size_t)(b * 128 + len) * 512 + tid];
    red[2 * tid] = bflo(u);
    red[2 * tid + 1] = bfhi(u);
  }
  __syncthreads();
  {
    const int col = tid >> 1, kh = tid & 1;
    const float4* w = (const float4*)(dsW + (size_t)col * D2H_ + kh * 512);
    float acc = 0.f;
#pragma unroll 8
    for (int k = 0; k < 128; ++k) {
      float4 l = ((const float4*)red)[kh * 128 + k];
      float4 q = w[k];
      acc = fmaf(l.x, q.x, fmaf(l.y, q.y, fmaf(l.z, q.z, fmaf(l.w, q.w, acc))));
    }
    acc += __shfl_xor(acc, 1);
    __syncthreads();
    if (kh == 0) hf[col] = acc + dsb[col];
    __syncthreads();
    if (tid < 256) hb2p[tid + (tid >> 6)] = pack2(hf[2 * tid], hf[2 * tid + 1]);
    __syncthreads();
  }

  auto attend = [&](int step) {
    // dp = h @ Wdec^T + bdec + benc (fp8 stream)
    {
      const uint2* wp = WD8 + (size_t)(kq * 32) * 256 + cg;
      float d0 = 0.f, d1 = 0.f;
#pragma unroll 8
      for (int c = 0; c < 32; ++c) {
        uint2 w = wp[(size_t)c * 256];
        uint32_t ha = hq[2 * c], hb = hq[2 * c + 1];
        floatx2 lo = up2_e4m3<false>(w.x), hi = up2_e4m3<true>(w.x);
        d0 = fmaf(bflo(ha), lo.x, fmaf(bfhi(ha), lo.y, fmaf(bflo(hb), hi.x, fmaf(bfhi(hb), hi.y, d0))));
        floatx2 lo1 = up2_e4m3<false>(w.y), hi1 = up2_e4m3<true>(w.y);
        d1 = fmaf(bflo(ha), lo1.x, fmaf(bfhi(ha), lo1.y, fmaf(bflo(hb), hi1.x, fmaf(bfhi(hb), hi1.y, d1))));
      }
      d0 += __shfl_xor(d0, 1); d0 += __shfl_xor(d0, 2);
      d1 += __shfl_xor(d1, 1); d1 += __shfl_xor(d1, 2);
      if (kq == 0) { dp[c0] = d0 + adb0; dp[c1] = d1 + adb1; }
    }
    __syncthreads();
    // scores from LDS encp_s
    {
      int t = tid >> 3, s8 = tid & 7;
      const uint32_t* ep = encp_s + t * 264 + s8;
      float s = 0.f;
#pragma unroll 4
      for (int i = 0; i < 32; ++i) {
        int j = s8 + 8 * i;
        uint32_t u = ep[8 * i];
        float2 d2 = *(const float2*)&dp[2 * j];
        float2 v2 = *(const float2*)&vavf[2 * j];
        s = fmaf(v2.x, tanhf_(bflo(u) + d2.x), s);
        s = fmaf(v2.y, tanhf_(bfhi(u) + d2.y), s);
      }
      s += __shfl_xor(s, 1);
      s += __shfl_xor(s, 2);
      s += __shfl_xor(s, 4);
      if (s8 == 0) sc[t] = s;
    }
    __syncthreads();
    if (tid < 128) sc[tid] = (msk[tid] > 0.f) ? sc[tid] + avb0 : -1e30f;
    __syncthreads();
    if (tid < 64) {
      float m = fmaxf(sc[tid], sc[tid + 64]);
#pragma unroll
      for (int o = 32; o > 0; o >>= 1) m = fmaxf(m, __shfl_xor(m, o));
      if (tid == 0) dpx[1] = m;
    }
    __syncthreads();
    if (tid < 128) pr[tid] = __expf(sc[tid] - dpx[1]);
    __syncthreads();
    if (tid < 64) {
      float s2 = pr[tid] + pr[tid + 64];
#pragma unroll
      for (int o = 32; o > 0; o >>= 1) s2 += __shfl_xor(s2, o);
      if (tid == 0) dpx[2] = s2;
    }
    __syncthreads();
    float inv = __builtin_amdgcn_rcpf(dpx[2]);
    if (tid < 128) {
      float v = pr[tid] * inv;
      pr[tid] = v;
      prp[tid + (tid >> 5)] = v;
    }
    __syncthreads();
    if (step >= 0) {
      // context = pr @ enc[b] -> HAb a-part
      const uint32_t* eb = (const uint32_t*)encb + (size_t)b * 128 * 512;
      int d = tid & 511, tq = tid >> 9;
      float x0 = 0.f, x1 = 0.f;
#pragma unroll 4
      for (int k = 0; k < 64; ++k) {
        int t = tq * 64 + k;
        float p = pr[t];
        uint32_t u = eb[(size_t)t * 512 + d];
        x0 = fmaf(p, bflo(u), x0);
        x1 = fmaf(p, bfhi(u), x1);
      }
      red[tid] = x0; red2[tid] = x1;
      __syncthreads();
      if (tid < 512) {
        x0 = red[tid] + red[tid + 512];
        x1 = red2[tid] + red2[tid + 512];
        uint32_t* hrow = (uint32_t*)(HAb + ((size_t)step * 32 + b) * G3_);
        hrow[256 + tid] = pack2(x0, x1);
      }
    }
    __syncthreads();
  };

  auto gru = [&](int i) {
    float xr0 = 0, xr1 = 0, xz0 = 0, xz1 = 0, xn0 = 0, xn1 = 0;
    // x-side: pr @ encW[b]  (fp8 stream)
    {
      const uint2* ep = EW8 + ((size_t)(b * 4 + kq) * 8) * 768 + cg;
      const float* pq = prp + kq * 33;
#pragma unroll
      for (int tq = 0; tq < 8; ++tq) {
        uint2 wr = ep[0];
        uint2 wz = ep[256];
        uint2 wn = ep[512];
        ep += 768;
        float p0 = pq[tq * 4], p1 = pq[tq * 4 + 1], p2 = pq[tq * 4 + 2], p3 = pq[tq * 4 + 3];
        floatx2 a0 = up2_e4m3<false>(wr.x), a1 = up2_e4m3<true>(wr.x);
        xr0 = fmaf(p0, a0.x, fmaf(p1, a0.y, fmaf(p2, a1.x, fmaf(p3, a1.y, xr0))));
        floatx2 b0_ = up2_e4m3<false>(wr.y), b1_ = up2_e4m3<true>(wr.y);
        xr1 = fmaf(p0, b0_.x, fmaf(p1, b0_.y, fmaf(p2, b1_.x, fmaf(p3, b1_.y, xr1))));
        floatx2 c0_ = up2_e4m3<false>(wz.x), c1_ = up2_e4m3<true>(wz.x);
        xz0 = fmaf(p0, c0_.x, fmaf(p1, c0_.y, fmaf(p2, c1_.x, fmaf(p3, c1_.y, xz0))));
        floatx2 d0_ = up2_e4m3<false>(wz.y), d1_ = up2_e4m3<true>(wz.y);
        xz1 = fmaf(p0, d0_.x, fmaf(p1, d0_.y, fmaf(p2, d1_.x, fmaf(p3, d1_.y, xz1))));
        floatx2 e0_ = up2_e4m3<false>(wn.x), e1_ = up2_e4m3<true>(wn.x);
        xn0 = fmaf(p0, e0_.x, fmaf(p1, e0_.y, fmaf(p2, e1_.x, fmaf(p3, e1_.y, xn0))));
        floatx2 f0_ = up2_e4m3<false>(wn.y), f1_ = up2_e4m3<true>(wn.y);
        xn1 = fmaf(p0, f0_.x, fmaf(p1, f0_.y, fmaf(p2, f1_.x, fmaf(p3, f1_.y, xn1))));
      }
    }
    float hr0 = 0, hr1 = 0, hz0 = 0, hz1 = 0, hn0 = 0, hn1 = 0;
    // h-side: h @ Whh^T  (fp8 stream)
    {
      const uint2* wp = WH8 + (size_t)(kq * 32) * 768 + cg;
#pragma unroll 8
      for (int c = 0; c < 32; ++c) {
        const uint2* w = wp + (size_t)c * 768;
        uint2 wr = w[0];
        uint2 wz = w[256];
        uint2 wn = w[512];
        uint32_t ha = hq[2 * c], hb = hq[2 * c + 1];
        floatx2 lo, hi;
        lo = up2_e4m3<false>(wr.x); hi = up2_e4m3<true>(wr.x);
        hr0 = fmaf(bflo(ha), lo.x, fmaf(bfhi(ha), lo.y, fmaf(bflo(hb), hi.x, fmaf(bfhi(hb), hi.y, hr0))));
        lo = up2_e4m3<false>(wr.y); hi = up2_e4m3<true>(wr.y);
        hr1 = fmaf(bflo(ha), lo.x, fmaf(bfhi(ha), lo.y, fmaf(bflo(hb), hi.x, fmaf(bfhi(hb), hi.y, hr1))));
        lo = up2_e4m3<false>(wz.x); hi = up2_e4m3<true>(wz.x);
        hz0 = fmaf(bflo(ha), lo.x, fmaf(bfhi(ha), lo.y, fmaf(bflo(hb), hi.x, fmaf(bfhi(hb), hi.y, hz0))));
        lo = up2_e4m3<false>(wz.y); hi = up2_e4m3<true>(wz.y);
        hz1 = fmaf(bflo(ha), lo.x, fmaf(bfhi(ha), lo.y, fmaf(bflo(hb), hi.x, fmaf(bfhi(hb), hi.y, hz1))));
        lo = up2_e4m3<false>(wn.x); hi = up2_e4m3<true>(wn.x);
        hn0 = fmaf(bflo(ha), lo.x, fmaf(bfhi(ha), lo.y, fmaf(bflo(hb), hi.x, fmaf(bfhi(hb), hi.y, hn0))));
        lo = up2_e4m3<false>(wn.y); hi = up2_e4m3<true>(wn.y);
        hn1 = fmaf(bflo(ha), lo.x, fmaf(bfhi(ha), lo.y, fmaf(bflo(hb), hi.x, fmaf(bfhi(hb), hi.y, hn1))));
      }
    }
    float tr0 = xr0 + hr0; tr0 += __shfl_xor(tr0, 1); tr0 += __shfl_xor(tr0, 2);
    float tr1 = xr1 + hr1; tr1 += __shfl_xor(tr1, 1); tr1 += __shfl_xor(tr1, 2);
    float tz0 = xz0 + hz0; tz0 += __shfl_xor(tz0, 1); tz0 += __shfl_xor(tz0, 2);
    float tz1 = xz1 + hz1; tz1 += __shfl_xor(tz1, 1); tz1 += __shfl_xor(tz1, 2);
    xn0 += __shfl_xor(xn0, 1); xn0 += __shfl_xor(xn0, 2);
    xn1 += __shfl_xor(xn1, 1); xn1 += __shfl_xor(xn1, 2);
    hn0 += __shfl_xor(hn0, 1); hn0 += __shfl_xor(hn0, 2);
    hn1 += __shfl_xor(hn1, 1); hn1 += __shfl_xor(hn1, 2);

    float hnew0 = 0.f, hnew1 = 0.f;
    if (kq == 0) {
      const float* xrow = XE + ((size_t)i * 32 + b) * G3_;
      float r0 = sigf(xrow[c0] + tr0 + db_r0);
      float r1 = sigf(xrow[c1] + tr1 + db_r1);
      float z0 = sigf(xrow[512 + c0] + tz0 + db_z0);
      float z1 = sigf(xrow[512 + c1] + tz1 + db_z1);
      float n0 = tanhf_(xrow[1024 + c0] + xn0 + r0 * (hn0 + db_n0));
      float n1 = tanhf_(xrow[1024 + c1] + xn1 + r1 * (hn1 + db_n1));
      hnew0 = (1.f - z0) * n0 + z0 * hf[c0];
      hnew1 = (1.f - z1) * n1 + z1 * hf[c1];
      ((uint32_t*)(HAb + ((size_t)i * 32 + b) * G3_))[cg] = pack2(hnew0, hnew1);
    }
    __syncthreads();
    if (kq == 0) {
      hf[c0] = hnew0; hf[c1] = hnew1;
      hb2p[cg + (cg >> 6)] = pack2(hnew0, hnew1);
    }
    __syncthreads();
  };

  attend(-1);
  for (int i = 0; i < 63; ++i) {
    gru(i);
    attend(i);
  }
}

// ---------------- launch ------------------------------------------------------

extern "C" void kernel_launch(void* const* d_in, const int* in_sizes, int n_in,
                              void* d_out, int out_size, void* d_ws, size_t ws_size,
                              hipStream_t stream) {
  const int*   inp     = (const int*)d_in[0];
  const int*   outi    = (const int*)d_in[1];
  const float* emb_inp = (const float*)d_in[2];
  const float* emb_out = (const float*)d_in[3];
  const float* eWih_f  = (const float*)d_in[4];
  const float* eWhh_f  = (const float*)d_in[5];
  const float* ebih_f  = (const float*)d_in[6];
  const float* ebhh_f  = (const float*)d_in[7];
  const float* eWih_b  = (const float*)d_in[8];
  const float* eWhh_b  = (const float*)d_in[9];
  const float* ebih_b  = (const float*)d_in[10];
  const float* ebhh_b  = (const float*)d_in[11];
  const float* dsW     = (const float*)d_in[12];
  const float* dsb     = (const float*)d_in[13];
  const float* dWih    = (const float*)d_in[14];
  const float* dWhh    = (const float*)d_in[15];
  const float* dbih    = (const float*)d_in[16];
  const float* dbhh    = (const float*)d_in[17];
  const float* aWenc   = (const float*)d_in[18];
  const float* abenc   = (const float*)d_in[19];
  const float* aWdec   = (const float*)d_in[20];
  const float* abdec   = (const float*)d_in[21];
  const float* av      = (const float*)d_in[22];
  const float* avb     = (const float*)d_in[23];
  const float* lW      = (const float*)d_in[24];
  const float* lb      = (const float*)d_in[25];
  float* dout = (float*)d_out;

  char* ws = (char*)d_ws;
  size_t off = 0;
  auto alloc = [&](size_t bytes) {
    void* p = ws + off;
    off += (bytes + 255) & ~(size_t)255;
    return p;
  };
  unsigned short* xb      = (unsigned short*)alloc((size_t)4096 * 256 * 2);
  unsigned short* xeb     = (unsigned short*)alloc((size_t)2016 * 256 * 2);
  unsigned short* xpb_f   = (unsigned short*)alloc((size_t)4096 * G3_ * 2);
  unsigned short* xpb_b   = (unsigned short*)alloc((size_t)4096 * G3_ * 2);
  unsigned short* encb    = (unsigned short*)alloc((size_t)4096 * D2H_ * 2);
  unsigned short* encpb   = (unsigned short*)alloc((size_t)4096 * 512 * 2);
  unsigned short* encWA   = (unsigned short*)alloc((size_t)4096 * G3_ * 2);
  uint2*          EW8     = (uint2*)alloc((size_t)786432 * 8);
  float*          XE      = (float*)alloc((size_t)2016 * G3_ * 4);
  unsigned short* HAb     = (unsigned short*)alloc((size_t)2048 * G3_ * 2);
  unsigned short* lWb     = (unsigned short*)alloc((size_t)VO_ * G3_ * 2);
  uint2*          W8f     = (uint2*)alloc((size_t)98304 * 8);
  uint2*          W8b     = (uint2*)alloc((size_t)98304 * 8);
  uint2*          WH8     = (uint2*)alloc((size_t)98304 * 8);
  uint2*          WD8     = (uint2*)alloc((size_t)32768 * 8);
  unsigned short* dWihb   = (unsigned short*)alloc((size_t)G3_ * 1280 * 2);
  unsigned short* aWencb  = (unsigned short*)alloc((size_t)512 * D2H_ * 2);
  unsigned short* eWihb_f = (unsigned short*)alloc((size_t)G3_ * 256 * 2);
  unsigned short* eWihb_b = (unsigned short*)alloc((size_t)G3_ * 256 * 2);

  // init + conversions
  k_init<<<192, 256, 0, stream>>>(HAb + (size_t)2016 * G3_);
  k_cvt_multi<<<1600, 256, 0, stream>>>(dWih, dWihb, aWenc, aWencb,
                                        eWih_f, eWihb_f, eWih_b, eWihb_b);
  k_cvt_w8<<<1280, 256, 0, stream>>>(eWhh_f, W8f, eWhh_b, W8b, dWhh, WH8, aWdec, WD8);
  k_cvt_bf16<<<24000, 256, 0, stream>>>(lW, lWb, VO_ * G3_ / 8);

  // embeddings
  k_gather_xb<<<512, 256, 0, stream>>>(inp, emb_inp, xb);
  k_gather_xeb<<<252, 256, 0, stream>>>(outi, emb_out, xeb);

  // xp = x @ eWih^T + ebih  (bf16 out)
  {
    dim3 g(12, 32);
    k_bgemm<1><<<g, 256, 0, stream>>>(xb, 256, eWihb_f, 256, ebih_f, xpb_f, G3_, 4096, G3_, 256);
    k_bgemm<1><<<g, 256, 0, stream>>>(xb, 256, eWihb_b, 256, ebih_b, xpb_b, G3_, 4096, G3_, 256);
  }

  // encoder (32 blocks, 2 chains each, fp8 weights)
  k_encoder<<<32, 1024, 0, stream>>>(xpb_f, xpb_b, W8f, ebhh_f, W8b, ebhh_b, encb);

  // enc_proj (bias folded into decoder dp)
  {
    dim3 g(4, 32);
    k_bgemm<1><<<g, 256, 0, stream>>>(encb, D2H_, aWencb, D2H_, nullptr, encpb, 512, 4096, 512, D2H_);
  }
  // encWA = enc @ dWih_a^T  [4096][1536] bf16, then fp8 repack
  {
    dim3 g(12, 32);
    k_bgemm<1><<<g, 256, 0, stream>>>(encb, D2H_, dWihb + 256, 1280, nullptr, encWA, G3_, 4096, G3_, D2H_);
  }
  k_packEW8<<<3072, 256, 0, stream>>>(encWA, EW8);

  // XE = xe @ dWih_e^T + dbih (f32 out)
  {
    dim3 g(12, 16);
    k_bgemm<0><<<g, 256, 0, stream>>>(xeb, 256, dWihb, 1280, dbih, XE, G3_, 2016, G3_, 256);
  }

  // decoder (fp8 weight streams)
  k_decoder<<<32, 1024, 0, stream>>>(inp, encb, encpb, XE, EW8, WH8, WD8,
                                     dsW, dsb, dbhh, abdec, abenc, av, avb, HAb);

  // logits
  {
    dim3 g(250, 16);
    k_bgemm<3><<<g, 256, 0, stream>>>(HAb, G3_, lWb, G3_, lb, dout, 0, 2016, VO_, G3_);
  }
  k_first<<<4000, 256, 0, stream>>>(dout);
}